// Round 10
// baseline (200.701 us; speedup 1.0000x reference)
//
#include <hip/hip_runtime.h>
#include <hip/hip_bf16.h>

#define Bb 8
#define Cc 64
#define Tt 16
#define Hh 56
#define Ww 56
#define COUT 128
#define HW (Hh*Ww)            // 3136
#define THW (Tt*HW)           // 50176
#define NPG ((double)(32*THW))
#define NBLK23 392u

typedef __attribute__((ext_vector_type(8))) short short8v;   // 8 bf16
typedef __attribute__((ext_vector_type(4))) float f32x4;

__device__ __forceinline__ unsigned short f2bf(float x) {
  __hip_bfloat16 h = __float2bfloat16(x);
  return *reinterpret_cast<unsigned short*>(&h);
}
__device__ __forceinline__ float blo(unsigned int u) {
  return __uint_as_float(u << 16);
}
__device__ __forceinline__ float bhi(unsigned int u) {
  return __uint_as_float(u & 0xFFFF0000u);
}
__device__ __forceinline__ unsigned int pack2(float a, float b) {
  return (unsigned int)f2bf(a) | ((unsigned int)f2bf(b) << 16);
}

// ---------------------------------------------------------------------------
// K1: fused depthwise spatial 3x3 + temporal 3-tap. One block per
// (b, channel-PAIR, t-quad). raw & ring planes in LDS as packed bf16 pairs.
// Block 0 zeroes stats + barrier counter (k23 runs after, stream-ordered).
// ---------------------------------------------------------------------------
__global__ __launch_bounds__(256) void k1_dwconv(
    const float* __restrict__ x,  const float* __restrict__ sw,
    const float* __restrict__ sb, const float* __restrict__ tw,
    const float* __restrict__ tb, unsigned int* __restrict__ zq,
    double* __restrict__ stats, unsigned int* __restrict__ ctr)
{
  __shared__ unsigned int raw[HW];        // 12.25 KB (bf16 pair)
  __shared__ unsigned int ring[3][HW];    // 36.75 KB

  const int tid = threadIdx.x;
  if (blockIdx.x == 0) {
    if (tid < 64) stats[tid] = 0.0;
    if (tid == 64) *ctr = 0u;
  }

  const int tq = blockIdx.x & 3;
  const int c2 = (blockIdx.x >> 2) & 31;
  const int b  =  blockIdx.x >> 7;
  const int t0 = tq * 4;
  const int ca = c2 * 2, cb = ca + 1;

  float s9a[9], s9b[9];
#pragma unroll
  for (int k = 0; k < 9; ++k) { s9a[k] = sw[ca * 9 + k]; s9b[k] = sw[cb * 9 + k]; }
  float ta3[3], tb3[3];
#pragma unroll
  for (int k = 0; k < 3; ++k) { ta3[k] = tw[ca * 3 + k]; tb3[k] = tw[cb * 3 + k]; }
  const float sba = sb[ca], sbb = sb[cb];
  const float tba = tb[ca], tbb = tb[cb];

  const float* xa = x + (size_t)(b * Cc + ca) * THW;
  const float* xb = x + (size_t)(b * Cc + cb) * THW;
  unsigned int* zbase = zq + (size_t)(b * 32 + c2) * THW;

  for (int tt = t0 - 1; tt <= t0 + 4; ++tt) {
    if (tt >= 0 && tt < Tt) {
      const float* xpa = xa + tt * HW;
      const float* xpb = xb + tt * HW;
      for (int f = tid; f < HW / 4; f += 256) {
        float4 va = *(const float4*)(xpa + f * 4);
        float4 vb = *(const float4*)(xpb + f * 4);
        uint4 pk;
        pk.x = pack2(va.x, vb.x);
        pk.y = pack2(va.y, vb.y);
        pk.z = pack2(va.z, vb.z);
        pk.w = pack2(va.w, vb.w);
        *(uint4*)&raw[f * 4] = pk;
      }
    }
    __syncthreads();

    if (tt >= 0 && tt < Tt) {
      unsigned int* rg = ring[tt % 3];
      for (int q = tid; q < HW / 4; q += 256) {
        int h  = q / 14;
        int w0 = (q - h * 14) * 4;
        float sa0 = sba, sa1 = sba, sa2 = sba, sa3 = sba;
        float sb0 = sbb, sb1 = sbb, sb2 = sbb, sb3 = sbb;
#pragma unroll
        for (int dh = -1; dh <= 1; ++dh) {
          int hh = h + dh;
          if (hh < 0 || hh > Hh - 1) continue;
          const unsigned int* rr = &raw[hh * Ww + w0];
          uint4 mv = *(const uint4*)rr;
          unsigned int lf = (w0 > 0)      ? rr[-1] : 0u;
          unsigned int rt = (w0 < Ww - 4) ? rr[4]  : 0u;
          float am1 = blo(lf),  a0 = blo(mv.x), a1 = blo(mv.y);
          float a2  = blo(mv.z), a3 = blo(mv.w), a4 = blo(rt);
          float bm1 = bhi(lf),  b0 = bhi(mv.x), b1 = bhi(mv.y);
          float b2  = bhi(mv.z), b3 = bhi(mv.w), b4 = bhi(rt);
          float k0a = s9a[(dh + 1) * 3 + 0], k1a = s9a[(dh + 1) * 3 + 1], k2a = s9a[(dh + 1) * 3 + 2];
          float k0b = s9b[(dh + 1) * 3 + 0], k1b = s9b[(dh + 1) * 3 + 1], k2b = s9b[(dh + 1) * 3 + 2];
          sa0 = fmaf(k0a, am1, fmaf(k1a, a0, fmaf(k2a, a1, sa0)));
          sa1 = fmaf(k0a, a0,  fmaf(k1a, a1, fmaf(k2a, a2, sa1)));
          sa2 = fmaf(k0a, a1,  fmaf(k1a, a2, fmaf(k2a, a3, sa2)));
          sa3 = fmaf(k0a, a2,  fmaf(k1a, a3, fmaf(k2a, a4, sa3)));
          sb0 = fmaf(k0b, bm1, fmaf(k1b, b0, fmaf(k2b, b1, sb0)));
          sb1 = fmaf(k0b, b0,  fmaf(k1b, b1, fmaf(k2b, b2, sb1)));
          sb2 = fmaf(k0b, b1,  fmaf(k1b, b2, fmaf(k2b, b3, sb2)));
          sb3 = fmaf(k0b, b2,  fmaf(k1b, b3, fmaf(k2b, b4, sb3)));
        }
        uint4 pk;
        pk.x = pack2(sa0, sb0);
        pk.y = pack2(sa1, sb1);
        pk.z = pack2(sa2, sb2);
        pk.w = pack2(sa3, sb3);
        *(uint4*)&rg[q * 4] = pk;
      }
    }
    __syncthreads();

    int t_out = tt - 1;
    if (t_out >= t0 && t_out <= t0 + 3) {
      unsigned int* zp = zbase + (size_t)t_out * HW;
      for (int q = tid; q < HW / 4; q += 256) {
        float aa0 = tba, aa1 = tba, aa2 = tba, aa3 = tba;
        float bb0 = tbb, bb1 = tbb, bb2 = tbb, bb3 = tbb;
#pragma unroll
        for (int dt = -1; dt <= 1; ++dt) {
          int ti = t_out + dt;
          if (ti < 0 || ti > Tt - 1) continue;
          float tka = ta3[dt + 1], tkb = tb3[dt + 1];
          uint4 v = *(const uint4*)&ring[ti % 3][q * 4];
          aa0 = fmaf(tka, blo(v.x), aa0);  bb0 = fmaf(tkb, bhi(v.x), bb0);
          aa1 = fmaf(tka, blo(v.y), aa1);  bb1 = fmaf(tkb, bhi(v.y), bb1);
          aa2 = fmaf(tka, blo(v.z), aa2);  bb2 = fmaf(tkb, bhi(v.z), bb2);
          aa3 = fmaf(tka, blo(v.w), aa3);  bb3 = fmaf(tkb, bhi(v.w), bb3);
        }
        uint4 o;
        o.x = pack2(aa0, bb0);
        o.y = pack2(aa1, bb1);
        o.z = pack2(aa2, bb2);
        o.w = pack2(aa3, bb3);
        *(uint4*)(zp + q * 4) = o;
      }
    }
    __syncthreads();
  }
}

// ---------------------------------------------------------------------------
// K23 (plain kernel + manual barrier): 392 blocks x 2 tiles. Phase 1 = stats
// GEMM over both tiles; device barrier (all 392 co-resident by construction:
// launch_bounds(256,2) => VGPR<=256 => 2 blocks/CU => capacity 512);
// phase 2 = re-stage (L2-warm) + re-GEMM + GroupNorm + ReLU + store.
// ---------------------------------------------------------------------------
#define WFRAG_LOAD()                                                           \
  const int lr = tid & 15, lg = (tid >> 4) & 3, wv = tid >> 6;                 \
  const int obase = wv * 32;                                                   \
  short8v wfrag[2][2];                                                         \
  _Pragma("unroll")                                                            \
  for (int ot = 0; ot < 2; ++ot)                                               \
    _Pragma("unroll")                                                          \
    for (int kt = 0; kt < 2; ++kt) {                                           \
      int o  = obase + ot * 16 + lr;                                           \
      int c0 = kt * 32 + lg * 8;                                               \
      float4 wa = *(const float4*)(pw + o * 64 + c0);                          \
      float4 wb = *(const float4*)(pw + o * 64 + c0 + 4);                      \
      short8v fr;                                                              \
      fr[0] = (short)f2bf(wa.x); fr[1] = (short)f2bf(wa.y);                    \
      fr[2] = (short)f2bf(wa.z); fr[3] = (short)f2bf(wa.w);                    \
      fr[4] = (short)f2bf(wb.x); fr[5] = (short)f2bf(wb.y);                    \
      fr[6] = (short)f2bf(wb.z); fr[7] = (short)f2bf(wb.w);                    \
      wfrag[ot][kt] = fr;                                                      \
    }

#define LDR(it) {                                                              \
  int p0 = (it) * 128;                                                         \
  _Pragma("unroll")                                                            \
  for (int i = 0; i < 4; ++i) {                                                \
    int f = tid + i * 256; int c2r = f >> 5; int po = (f & 31) << 2;           \
    st[i] = *(const uint4*)(zb + (size_t)c2r * THW + p0 + po);                 \
  } }

#define STL(bf) {                                                              \
  _Pragma("unroll")                                                            \
  for (int i = 0; i < 4; ++i) {                                                \
    int f = tid + i * 256; int c2r = f >> 5; int po = (f & 31) << 2;           \
    *(uint4*)&zt[bf][c2r * 132 + po] = st[i];                                  \
  } }

#define MFMA_TILE(bufidx)                                                      \
  f32x4 acc[2][8];                                                             \
  _Pragma("unroll")                                                            \
  for (int ot = 0; ot < 2; ++ot)                                               \
    _Pragma("unroll")                                                          \
    for (int pt = 0; pt < 8; ++pt) {                                           \
      acc[ot][pt][0] = 0.f; acc[ot][pt][1] = 0.f;                              \
      acc[ot][pt][2] = 0.f; acc[ot][pt][3] = 0.f;                              \
    }                                                                          \
  {                                                                            \
    const unsigned int* ztc = zt[bufidx];                                      \
    _Pragma("unroll")                                                          \
    for (int kt = 0; kt < 2; ++kt) {                                           \
      const int c2b = kt * 16 + lg * 4;                                        \
      _Pragma("unroll")                                                        \
      for (int pt = 0; pt < 8; ++pt) {                                         \
        const unsigned int* zp2 = &ztc[c2b * 132 + pt * 16 + lr];              \
        union { unsigned int u[4]; short8v s; } zfu;                           \
        zfu.u[0] = zp2[0];   zfu.u[1] = zp2[132];                              \
        zfu.u[2] = zp2[264]; zfu.u[3] = zp2[396];                              \
        acc[0][pt] = __builtin_amdgcn_mfma_f32_16x16x32_bf16(                  \
            zfu.s, wfrag[0][kt], acc[0][pt], 0, 0, 0);                         \
        acc[1][pt] = __builtin_amdgcn_mfma_f32_16x16x32_bf16(                  \
            zfu.s, wfrag[1][kt], acc[1][pt], 0, 0, 0);                         \
      }                                                                        \
    }                                                                          \
  }

__global__ __launch_bounds__(256, 2) void k23_fused(
    const unsigned int* __restrict__ zq, const float* __restrict__ pw,
    const float* __restrict__ pb, double* __restrict__ stats,
    unsigned int* __restrict__ ctr,
    const float* __restrict__ gnw, const float* __restrict__ gnb,
    float* __restrict__ out)
{
  __shared__ unsigned int zt[2][32 * 132];   // 33.8 KB
  const int tid = threadIdx.x;
  const int tile0 = blockIdx.x * 2;
  const int b   = tile0 / 98;                 // both tiles share b (98 even)
  const int pg0 = tile0 - b * 98;

  WFRAG_LOAD();
  const float pbl[2] = { pb[obase + lr], pb[obase + 16 + lr] };

  uint4 st[4];

  // -------- phase 1: stats over both tiles --------
  float s1 = 0.0f, s2 = 0.0f;
  for (int j = 0; j < 2; ++j) {
    const unsigned int* zb = zq + (size_t)(b * 32) * THW + (pg0 + j) * 512;
    LDR(0); STL(0);
    for (int it = 0; it < 4; ++it) {
      __syncthreads();
      if (it < 3) LDR(it + 1);
      MFMA_TILE(it & 1);
      if (it < 3) STL((it + 1) & 1);
#pragma unroll
      for (int ot = 0; ot < 2; ++ot)
#pragma unroll
        for (int pt = 0; pt < 8; ++pt)
#pragma unroll
          for (int r = 0; r < 4; ++r) {
            float d = acc[ot][pt][r] + pbl[ot];
            s1 += d;
            s2 = fmaf(d, d, s2);
          }
    }
    __syncthreads();   // all waves done reading zt before next tile restages
  }
#pragma unroll
  for (int off = 32; off; off >>= 1) {
    s1 += __shfl_xor(s1, off);
    s2 += __shfl_xor(s2, off);
  }
  if ((tid & 63) == 0) {
    atomicAdd(&stats[(b * 4 + wv) * 2 + 0], (double)s1);
    atomicAdd(&stats[(b * 4 + wv) * 2 + 1], (double)s2);
  }

  // -------- device-wide barrier (all 392 blocks co-resident) --------
  __syncthreads();                 // drains this block's stats atomics
  if (tid == 0) {
    __threadfence();
    atomicAdd(ctr, 1u);
    while (__hip_atomic_load(ctr, __ATOMIC_ACQUIRE, __HIP_MEMORY_SCOPE_AGENT)
           < NBLK23) {
      __builtin_amdgcn_s_sleep(32);
    }
  }
  __syncthreads();

  // -------- phase 2: normalize + store --------
  double sm1 = __hip_atomic_load(&stats[(b * 4 + wv) * 2 + 0],
                                 __ATOMIC_ACQUIRE, __HIP_MEMORY_SCOPE_AGENT);
  double sm2 = __hip_atomic_load(&stats[(b * 4 + wv) * 2 + 1],
                                 __ATOMIC_ACQUIRE, __HIP_MEMORY_SCOPE_AGENT);
  double md = sm1 / NPG;
  double vd = sm2 / NPG - md * md;
  float m   = (float)md;
  float inv = rsqrtf((float)vd + 1e-5f);

  float Ac[2], Bc[2];
#pragma unroll
  for (int ot = 0; ot < 2; ++ot) {
    int o = obase + ot * 16 + lr;
    float A = inv * gnw[o];
    Ac[ot] = A;
    Bc[ot] = fmaf(pb[o] - m, A, gnb[o]);
  }

  for (int j = 0; j < 2; ++j) {
    const unsigned int* zb = zq + (size_t)(b * 32) * THW + (pg0 + j) * 512;
    float* ob = out + (size_t)(b * COUT) * THW + (pg0 + j) * 512 + lg * 4;
    LDR(0); STL(0);
    for (int it = 0; it < 4; ++it) {
      __syncthreads();
      if (it < 3) LDR(it + 1);
      MFMA_TILE(it & 1);
      if (it < 3) STL((it + 1) & 1);
#pragma unroll
      for (int ot = 0; ot < 2; ++ot) {
        int o = obase + ot * 16 + lr;
        float A = Ac[ot], B = Bc[ot];
        float* orow = ob + (size_t)o * THW + it * 128;
#pragma unroll
        for (int pt = 0; pt < 8; ++pt) {
          f32x4 a = acc[ot][pt];
          float4 v;
          v.x = fmaf(a[0], A, B); v.x = v.x > 0.0f ? v.x : 0.0f;
          v.y = fmaf(a[1], A, B); v.y = v.y > 0.0f ? v.y : 0.0f;
          v.z = fmaf(a[2], A, B); v.z = v.z > 0.0f ? v.z : 0.0f;
          v.w = fmaf(a[3], A, B); v.w = v.w > 0.0f ? v.w : 0.0f;
          *(float4*)(orow + pt * 16) = v;
        }
      }
    }
    __syncthreads();
  }
}

// ---------------------------------------------------------------------------
extern "C" void kernel_launch(void* const* d_in, const int* in_sizes, int n_in,
                              void* d_out, int out_size, void* d_ws, size_t ws_size,
                              hipStream_t stream)
{
  const float* x   = (const float*)d_in[0];
  const float* sw  = (const float*)d_in[1];
  const float* sb  = (const float*)d_in[2];
  const float* tw  = (const float*)d_in[3];
  const float* tb  = (const float*)d_in[4];
  const float* pw  = (const float*)d_in[5];
  const float* pb  = (const float*)d_in[6];
  const float* gnw = (const float*)d_in[7];
  const float* gnb = (const float*)d_in[8];
  float* out = (float*)d_out;

  double* stats     = (double*)d_ws;                        // 64 doubles
  unsigned int* ctr = (unsigned int*)((char*)d_ws + 512);   // barrier counter
  unsigned int* zq  = (unsigned int*)((char*)d_ws + 1024);  // bf16-pair z

  k1_dwconv<<<Bb * 32 * 4, 256, 0, stream>>>(x, sw, sb, tw, tb, zq, stats, ctr);
  k23_fused<<<NBLK23, 256, 0, stream>>>(zq, pw, pb, stats, ctr, gnw, gnb, out);
}

// Round 11
// 173.667 us; speedup vs baseline: 1.1557x; 1.1557x over previous
//
#include <hip/hip_runtime.h>
#include <hip/hip_bf16.h>

#define Bb 8
#define Cc 64
#define Tt 16
#define Hh 56
#define Ww 56
#define COUT 128
#define HW (Hh*Ww)            // 3136
#define THW (Tt*HW)           // 50176
#define NPG ((double)(32*THW))

typedef __attribute__((ext_vector_type(8))) short short8v;   // 8 bf16
typedef __attribute__((ext_vector_type(4))) float f32x4;

__device__ __forceinline__ unsigned short f2bf(float x) {
  __hip_bfloat16 h = __float2bfloat16(x);
  return *reinterpret_cast<unsigned short*>(&h);
}
__device__ __forceinline__ float blo(unsigned int u) {
  return __uint_as_float(u << 16);
}
__device__ __forceinline__ float bhi(unsigned int u) {
  return __uint_as_float(u & 0xFFFF0000u);
}
__device__ __forceinline__ unsigned int pack2(float a, float b) {
  return (unsigned int)f2bf(a) | ((unsigned int)f2bf(b) << 16);
}

// ---------------------------------------------------------------------------
// K1: fused depthwise spatial 3x3 + temporal 3-tap. One block per
// (b, channel-PAIR, t-quad). Next x-plane is prefetched into REGISTERS while
// the current plane's spatial/temporal compute runs (hides HBM latency).
// Block 0 zeroes the stats buffer (k2 runs after, stream-ordered).
// ---------------------------------------------------------------------------
__global__ __launch_bounds__(256) void k1_dwconv(
    const float* __restrict__ x,  const float* __restrict__ sw,
    const float* __restrict__ sb, const float* __restrict__ tw,
    const float* __restrict__ tb, unsigned int* __restrict__ zq,
    double* __restrict__ stats)
{
  __shared__ unsigned int raw[HW];        // 12.25 KB (bf16 pair)
  __shared__ unsigned int ring[3][HW];    // 36.75 KB

  const int tid = threadIdx.x;
  if (blockIdx.x == 0 && tid < 64) stats[tid] = 0.0;

  const int tq = blockIdx.x & 3;
  const int c2 = (blockIdx.x >> 2) & 31;
  const int b  =  blockIdx.x >> 7;
  const int t0 = tq * 4;
  const int ca = c2 * 2, cb = ca + 1;

  float s9a[9], s9b[9];
#pragma unroll
  for (int k = 0; k < 9; ++k) { s9a[k] = sw[ca * 9 + k]; s9b[k] = sw[cb * 9 + k]; }
  float ta3[3], tb3[3];
#pragma unroll
  for (int k = 0; k < 3; ++k) { ta3[k] = tw[ca * 3 + k]; tb3[k] = tw[cb * 3 + k]; }
  const float sba = sb[ca], sbb = sb[cb];
  const float tba = tb[ca], tbb = tb[cb];

  const float* xa = x + (size_t)(b * Cc + ca) * THW;
  const float* xb = x + (size_t)(b * Cc + cb) * THW;
  unsigned int* zbase = zq + (size_t)(b * 32 + c2) * THW;

  float4 pA[4], pB[4], qA[4], qB[4];

#define LOADP(TT, RA, RB) {                                                    \
    int _t = (TT);                                                             \
    if (_t >= 0 && _t < Tt && _t <= t0 + 4) {                                  \
      const float* _xa = xa + _t * HW;                                         \
      const float* _xb = xb + _t * HW;                                         \
      _Pragma("unroll")                                                        \
      for (int i = 0; i < 4; ++i) {                                            \
        int f = tid + i * 256;                                                 \
        if (f < HW / 4) {                                                      \
          RA[i] = *(const float4*)(_xa + f * 4);                               \
          RB[i] = *(const float4*)(_xb + f * 4);                               \
        }                                                                      \
      }                                                                        \
    } }

#define RAWW(RA, RB) {                                                         \
    _Pragma("unroll")                                                          \
    for (int i = 0; i < 4; ++i) {                                              \
      int f = tid + i * 256;                                                   \
      if (f < HW / 4) {                                                        \
        uint4 pk;                                                              \
        pk.x = pack2(RA[i].x, RB[i].x);                                        \
        pk.y = pack2(RA[i].y, RB[i].y);                                        \
        pk.z = pack2(RA[i].z, RB[i].z);                                        \
        pk.w = pack2(RA[i].w, RB[i].w);                                        \
        *(uint4*)&raw[f * 4] = pk;                                             \
      }                                                                        \
    } }

  LOADP(t0 - 1, pA, pB);

#pragma unroll
  for (int k = 0; k < 6; ++k) {
    const int tt = t0 - 1 + k;
    const bool val = (tt >= 0 && tt < Tt);

    // stage current plane (from regs) into raw; issue next-plane loads
    if (k & 1) {
      if (val) RAWW(qA, qB);
      LOADP(tt + 1, pA, pB);
    } else {
      if (val) RAWW(pA, pB);
      LOADP(tt + 1, qA, qB);
    }
    __syncthreads();

    // spatial 3x3: raw -> ring[tt%3]
    if (val) {
      unsigned int* rg = ring[tt % 3];
      for (int q = tid; q < HW / 4; q += 256) {
        int h  = q / 14;
        int w0 = (q - h * 14) * 4;
        float sa0 = sba, sa1 = sba, sa2 = sba, sa3 = sba;
        float sb0 = sbb, sb1 = sbb, sb2 = sbb, sb3 = sbb;
#pragma unroll
        for (int dh = -1; dh <= 1; ++dh) {
          int hh = h + dh;
          if (hh < 0 || hh > Hh - 1) continue;
          const unsigned int* rr = &raw[hh * Ww + w0];
          uint4 mv = *(const uint4*)rr;
          unsigned int lf = (w0 > 0)      ? rr[-1] : 0u;
          unsigned int rt = (w0 < Ww - 4) ? rr[4]  : 0u;
          float am1 = blo(lf),  a0 = blo(mv.x), a1 = blo(mv.y);
          float a2  = blo(mv.z), a3 = blo(mv.w), a4 = blo(rt);
          float bm1 = bhi(lf),  b0 = bhi(mv.x), b1 = bhi(mv.y);
          float b2  = bhi(mv.z), b3 = bhi(mv.w), b4 = bhi(rt);
          float k0a = s9a[(dh + 1) * 3 + 0], k1a = s9a[(dh + 1) * 3 + 1], k2a = s9a[(dh + 1) * 3 + 2];
          float k0b = s9b[(dh + 1) * 3 + 0], k1b = s9b[(dh + 1) * 3 + 1], k2b = s9b[(dh + 1) * 3 + 2];
          sa0 = fmaf(k0a, am1, fmaf(k1a, a0, fmaf(k2a, a1, sa0)));
          sa1 = fmaf(k0a, a0,  fmaf(k1a, a1, fmaf(k2a, a2, sa1)));
          sa2 = fmaf(k0a, a1,  fmaf(k1a, a2, fmaf(k2a, a3, sa2)));
          sa3 = fmaf(k0a, a2,  fmaf(k1a, a3, fmaf(k2a, a4, sa3)));
          sb0 = fmaf(k0b, bm1, fmaf(k1b, b0, fmaf(k2b, b1, sb0)));
          sb1 = fmaf(k0b, b0,  fmaf(k1b, b1, fmaf(k2b, b2, sb1)));
          sb2 = fmaf(k0b, b1,  fmaf(k1b, b2, fmaf(k2b, b3, sb2)));
          sb3 = fmaf(k0b, b2,  fmaf(k1b, b3, fmaf(k2b, b4, sb3)));
        }
        uint4 pk;
        pk.x = pack2(sa0, sb0);
        pk.y = pack2(sa1, sb1);
        pk.z = pack2(sa2, sb2);
        pk.w = pack2(sa3, sb3);
        *(uint4*)&rg[q * 4] = pk;
      }
    }
    __syncthreads();

    // temporal emit t_out = tt-1 -> global z
    const int t_out = tt - 1;
    if (t_out >= t0 && t_out <= t0 + 3) {
      unsigned int* zp = zbase + (size_t)t_out * HW;
      for (int q = tid; q < HW / 4; q += 256) {
        float aa0 = tba, aa1 = tba, aa2 = tba, aa3 = tba;
        float bb0 = tbb, bb1 = tbb, bb2 = tbb, bb3 = tbb;
#pragma unroll
        for (int dt = -1; dt <= 1; ++dt) {
          int ti = t_out + dt;
          if (ti < 0 || ti > Tt - 1) continue;
          float tka = ta3[dt + 1], tkb = tb3[dt + 1];
          uint4 v = *(const uint4*)&ring[ti % 3][q * 4];
          aa0 = fmaf(tka, blo(v.x), aa0);  bb0 = fmaf(tkb, bhi(v.x), bb0);
          aa1 = fmaf(tka, blo(v.y), aa1);  bb1 = fmaf(tkb, bhi(v.y), bb1);
          aa2 = fmaf(tka, blo(v.z), aa2);  bb2 = fmaf(tkb, bhi(v.z), bb2);
          aa3 = fmaf(tka, blo(v.w), aa3);  bb3 = fmaf(tkb, bhi(v.w), bb3);
        }
        uint4 o;
        o.x = pack2(aa0, bb0);
        o.y = pack2(aa1, bb1);
        o.z = pack2(aa2, bb2);
        o.w = pack2(aa3, bb3);
        *(uint4*)(zp + q * 4) = o;
      }
    }
    // next iteration's __syncthreads (after RAWW) protects ring reuse
  }
#undef LOADP
#undef RAWW
}

// ---------------------------------------------------------------------------
// K2/K3: 128 pos x 128 out tile, 4 waves (wave = GN group), 4 subtiles/block,
// LDS double-buffer + 2-DEEP register prefetch (loads span a full iteration).
// MFMA: A = z (row = pos), B = W (col = o) -> lane owns o = lane&15,
// reg-quad = 4 consecutive positions.
// ---------------------------------------------------------------------------
#define WFRAG_LOAD()                                                           \
  const int lr = tid & 15, lg = (tid >> 4) & 3, wv = tid >> 6;                 \
  const int obase = wv * 32;                                                   \
  short8v wfrag[2][2];                                                         \
  _Pragma("unroll")                                                            \
  for (int ot = 0; ot < 2; ++ot)                                               \
    _Pragma("unroll")                                                          \
    for (int kt = 0; kt < 2; ++kt) {                                           \
      int o  = obase + ot * 16 + lr;                                           \
      int c0 = kt * 32 + lg * 8;                                               \
      float4 wa = *(const float4*)(pw + o * 64 + c0);                          \
      float4 wb = *(const float4*)(pw + o * 64 + c0 + 4);                      \
      short8v fr;                                                              \
      fr[0] = (short)f2bf(wa.x); fr[1] = (short)f2bf(wa.y);                    \
      fr[2] = (short)f2bf(wa.z); fr[3] = (short)f2bf(wa.w);                    \
      fr[4] = (short)f2bf(wb.x); fr[5] = (short)f2bf(wb.y);                    \
      fr[6] = (short)f2bf(wb.z); fr[7] = (short)f2bf(wb.w);                    \
      wfrag[ot][kt] = fr;                                                      \
    }

#define LDRV(it, S) {                                                          \
  int p0 = (it) * 128;                                                         \
  _Pragma("unroll")                                                            \
  for (int i = 0; i < 4; ++i) {                                                \
    int f = tid + i * 256; int c2r = f >> 5; int po = (f & 31) << 2;           \
    S[i] = *(const uint4*)(zb + (size_t)c2r * THW + p0 + po);                  \
  } }

#define STLV(S, bf) {                                                          \
  _Pragma("unroll")                                                            \
  for (int i = 0; i < 4; ++i) {                                                \
    int f = tid + i * 256; int c2r = f >> 5; int po = (f & 31) << 2;           \
    *(uint4*)&zt[bf][c2r * 132 + po] = S[i];                                   \
  } }

#define MFMA_TILE(bufidx)                                                      \
  f32x4 acc[2][8];                                                             \
  _Pragma("unroll")                                                            \
  for (int ot = 0; ot < 2; ++ot)                                               \
    _Pragma("unroll")                                                          \
    for (int pt = 0; pt < 8; ++pt) {                                           \
      acc[ot][pt][0] = 0.f; acc[ot][pt][1] = 0.f;                              \
      acc[ot][pt][2] = 0.f; acc[ot][pt][3] = 0.f;                              \
    }                                                                          \
  {                                                                            \
    const unsigned int* ztc = zt[bufidx];                                      \
    _Pragma("unroll")                                                          \
    for (int kt = 0; kt < 2; ++kt) {                                           \
      const int c2b = kt * 16 + lg * 4;                                        \
      _Pragma("unroll")                                                        \
      for (int pt = 0; pt < 8; ++pt) {                                         \
        const unsigned int* zp2 = &ztc[c2b * 132 + pt * 16 + lr];              \
        union { unsigned int u[4]; short8v s; } zfu;                           \
        zfu.u[0] = zp2[0];   zfu.u[1] = zp2[132];                              \
        zfu.u[2] = zp2[264]; zfu.u[3] = zp2[396];                              \
        acc[0][pt] = __builtin_amdgcn_mfma_f32_16x16x32_bf16(                  \
            zfu.s, wfrag[0][kt], acc[0][pt], 0, 0, 0);                         \
        acc[1][pt] = __builtin_amdgcn_mfma_f32_16x16x32_bf16(                  \
            zfu.s, wfrag[1][kt], acc[1][pt], 0, 0, 0);                         \
      }                                                                        \
    }                                                                          \
  }

#define STATS_BODY()                                                           \
  _Pragma("unroll")                                                            \
  for (int ot = 0; ot < 2; ++ot)                                               \
    _Pragma("unroll")                                                          \
    for (int pt = 0; pt < 8; ++pt)                                             \
      _Pragma("unroll")                                                        \
      for (int r = 0; r < 4; ++r) {                                            \
        float d = acc[ot][pt][r] + pbl[ot];                                    \
        s1 += d;                                                               \
        s2 = fmaf(d, d, s2);                                                   \
      }

// K2: GEMM over 4 subtiles -> per-(b,group) sum / sumsq (double atomics).
__global__ __launch_bounds__(256) void k2_stats(
    const unsigned int* __restrict__ zq, const float* __restrict__ pw,
    const float* __restrict__ pb, double* __restrict__ stats)
{
  __shared__ unsigned int zt[2][32 * 132];   // 33.8 KB
  const int tid = threadIdx.x;
  const int b  = blockIdx.x / 98;
  const int pg = blockIdx.x - b * 98;

  WFRAG_LOAD();
  const float pbl[2] = { pb[obase + lr], pb[obase + 16 + lr] };
  const unsigned int* zb = zq + (size_t)(b * 32) * THW + pg * 512;

  uint4 sA[4], sB[4];
  LDRV(0, sA); STLV(sA, 0); LDRV(1, sB);

  float s1 = 0.0f, s2 = 0.0f;
  __syncthreads();
  LDRV(2, sA);
  { MFMA_TILE(0); STLV(sB, 1); STATS_BODY(); }
  __syncthreads();
  LDRV(3, sB);
  { MFMA_TILE(1); STLV(sA, 0); STATS_BODY(); }
  __syncthreads();
  { MFMA_TILE(0); STLV(sB, 1); STATS_BODY(); }
  __syncthreads();
  { MFMA_TILE(1); STATS_BODY(); }

#pragma unroll
  for (int off = 32; off; off >>= 1) {
    s1 += __shfl_xor(s1, off);
    s2 += __shfl_xor(s2, off);
  }
  if ((tid & 63) == 0) {
    atomicAdd(&stats[(b * 4 + wv) * 2 + 0], (double)s1);
    atomicAdd(&stats[(b * 4 + wv) * 2 + 1], (double)s2);
  }
}

#define STORE_BODY(itn)                                                        \
  _Pragma("unroll")                                                            \
  for (int ot = 0; ot < 2; ++ot) {                                             \
    int o = obase + ot * 16 + lr;                                              \
    float A = Ac[ot], B = Bc[ot];                                              \
    float* orow = ob + (size_t)o * THW + (itn) * 128;                          \
    _Pragma("unroll")                                                          \
    for (int pt = 0; pt < 8; ++pt) {                                           \
      f32x4 a = acc[ot][pt];                                                   \
      float4 v;                                                                \
      v.x = fmaf(a[0], A, B); v.x = v.x > 0.0f ? v.x : 0.0f;                   \
      v.y = fmaf(a[1], A, B); v.y = v.y > 0.0f ? v.y : 0.0f;                   \
      v.z = fmaf(a[2], A, B); v.z = v.z > 0.0f ? v.z : 0.0f;                   \
      v.w = fmaf(a[3], A, B); v.w = v.w > 0.0f ? v.w : 0.0f;                   \
      *(float4*)(orow + pt * 16) = v;                                          \
    }                                                                          \
  }

// K3: GEMM recompute over 4 subtiles -> GroupNorm + affine + ReLU -> out.
__global__ __launch_bounds__(256) void k3_norm(
    const unsigned int* __restrict__ zq, const float* __restrict__ pw,
    const float* __restrict__ pb, const double* __restrict__ stats,
    const float* __restrict__ gnw, const float* __restrict__ gnb,
    float* __restrict__ out)
{
  __shared__ unsigned int zt[2][32 * 132];
  const int tid = threadIdx.x;
  const int b  = blockIdx.x / 98;
  const int pg = blockIdx.x - b * 98;

  WFRAG_LOAD();

  double sm1 = stats[(b * 4 + wv) * 2 + 0];
  double sm2 = stats[(b * 4 + wv) * 2 + 1];
  double md = sm1 / NPG;
  double vd = sm2 / NPG - md * md;
  float m   = (float)md;
  float inv = rsqrtf((float)vd + 1e-5f);

  float Ac[2], Bc[2];
#pragma unroll
  for (int ot = 0; ot < 2; ++ot) {
    int o = obase + ot * 16 + lr;
    float A = inv * gnw[o];
    Ac[ot] = A;
    Bc[ot] = fmaf(pb[o] - m, A, gnb[o]);
  }

  const unsigned int* zb = zq + (size_t)(b * 32) * THW + pg * 512;
  float* ob = out + (size_t)(b * COUT) * THW + pg * 512 + lg * 4;

  uint4 sA[4], sB[4];
  LDRV(0, sA); STLV(sA, 0); LDRV(1, sB);

  __syncthreads();
  LDRV(2, sA);
  { MFMA_TILE(0); STLV(sB, 1); STORE_BODY(0); }
  __syncthreads();
  LDRV(3, sB);
  { MFMA_TILE(1); STLV(sA, 0); STORE_BODY(1); }
  __syncthreads();
  { MFMA_TILE(0); STLV(sB, 1); STORE_BODY(2); }
  __syncthreads();
  { MFMA_TILE(1); STORE_BODY(3); }
}

// ---------------------------------------------------------------------------
extern "C" void kernel_launch(void* const* d_in, const int* in_sizes, int n_in,
                              void* d_out, int out_size, void* d_ws, size_t ws_size,
                              hipStream_t stream)
{
  const float* x   = (const float*)d_in[0];
  const float* sw  = (const float*)d_in[1];
  const float* sb  = (const float*)d_in[2];
  const float* tw  = (const float*)d_in[3];
  const float* tb  = (const float*)d_in[4];
  const float* pw  = (const float*)d_in[5];
  const float* pb  = (const float*)d_in[6];
  const float* gnw = (const float*)d_in[7];
  const float* gnb = (const float*)d_in[8];
  float* out = (float*)d_out;

  double* stats    = (double*)d_ws;                        // 64 doubles
  unsigned int* zq = (unsigned int*)((char*)d_ws + 512);   // bf16-pair z

  k1_dwconv<<<Bb * 32 * 4, 256, 0, stream>>>(x, sw, sb, tw, tb, zq, stats);
  k2_stats<<<Bb * 98, 256, 0, stream>>>(zq, pw, pb, stats);
  k3_norm <<<Bb * 98, 256, 0, stream>>>(zq, pw, pb, stats, gnw, gnb, out);
}

// Round 12
// 156.220 us; speedup vs baseline: 1.2847x; 1.1117x over previous
//
#include <hip/hip_runtime.h>
#include <hip/hip_bf16.h>

#define Bb 8
#define Cc 64
#define Tt 16
#define Hh 56
#define Ww 56
#define COUT 128
#define HW (Hh*Ww)            // 3136
#define THW (Tt*HW)           // 50176
#define NPG ((double)(32*THW))

typedef __attribute__((ext_vector_type(8))) short short8v;   // 8 bf16
typedef __attribute__((ext_vector_type(4))) float f32x4;

__device__ __forceinline__ unsigned short f2bf(float x) {
  __hip_bfloat16 h = __float2bfloat16(x);
  return *reinterpret_cast<unsigned short*>(&h);
}
__device__ __forceinline__ float blo(unsigned int u) {
  return __uint_as_float(u << 16);
}
__device__ __forceinline__ float bhi(unsigned int u) {
  return __uint_as_float(u & 0xFFFF0000u);
}
__device__ __forceinline__ unsigned int pack2(float a, float b) {
  return (unsigned int)f2bf(a) | ((unsigned int)f2bf(b) << 16);
}

// ---------------------------------------------------------------------------
// K1: fused depthwise spatial 3x3 + temporal 3-tap. One block per
// (b, channel-PAIR, t-quad). raw & ring planes in LDS as packed bf16 pairs.
// Block 0 zeroes the stats buffer (k2 runs after, stream-ordered).
// ---------------------------------------------------------------------------
__global__ __launch_bounds__(256) void k1_dwconv(
    const float* __restrict__ x,  const float* __restrict__ sw,
    const float* __restrict__ sb, const float* __restrict__ tw,
    const float* __restrict__ tb, unsigned int* __restrict__ zq,
    double* __restrict__ stats)
{
  __shared__ unsigned int raw[HW];        // 12.25 KB (bf16 pair)
  __shared__ unsigned int ring[3][HW];    // 36.75 KB

  const int tid = threadIdx.x;
  if (blockIdx.x == 0 && tid < 64) stats[tid] = 0.0;

  const int tq = blockIdx.x & 3;
  const int c2 = (blockIdx.x >> 2) & 31;
  const int b  =  blockIdx.x >> 7;
  const int t0 = tq * 4;
  const int ca = c2 * 2, cb = ca + 1;

  float s9a[9], s9b[9];
#pragma unroll
  for (int k = 0; k < 9; ++k) { s9a[k] = sw[ca * 9 + k]; s9b[k] = sw[cb * 9 + k]; }
  float ta3[3], tb3[3];
#pragma unroll
  for (int k = 0; k < 3; ++k) { ta3[k] = tw[ca * 3 + k]; tb3[k] = tw[cb * 3 + k]; }
  const float sba = sb[ca], sbb = sb[cb];
  const float tba = tb[ca], tbb = tb[cb];

  const float* xa = x + (size_t)(b * Cc + ca) * THW;
  const float* xb = x + (size_t)(b * Cc + cb) * THW;
  unsigned int* zbase = zq + (size_t)(b * 32 + c2) * THW;

  for (int tt = t0 - 1; tt <= t0 + 4; ++tt) {
    if (tt >= 0 && tt < Tt) {
      const float* xpa = xa + tt * HW;
      const float* xpb = xb + tt * HW;
      for (int f = tid; f < HW / 4; f += 256) {
        float4 va = *(const float4*)(xpa + f * 4);
        float4 vb = *(const float4*)(xpb + f * 4);
        uint4 pk;
        pk.x = pack2(va.x, vb.x);
        pk.y = pack2(va.y, vb.y);
        pk.z = pack2(va.z, vb.z);
        pk.w = pack2(va.w, vb.w);
        *(uint4*)&raw[f * 4] = pk;
      }
    }
    __syncthreads();

    if (tt >= 0 && tt < Tt) {
      unsigned int* rg = ring[tt % 3];
      for (int q = tid; q < HW / 4; q += 256) {
        int h  = q / 14;
        int w0 = (q - h * 14) * 4;
        float sa0 = sba, sa1 = sba, sa2 = sba, sa3 = sba;
        float sb0 = sbb, sb1 = sbb, sb2 = sbb, sb3 = sbb;
#pragma unroll
        for (int dh = -1; dh <= 1; ++dh) {
          int hh = h + dh;
          if (hh < 0 || hh > Hh - 1) continue;
          const unsigned int* rr = &raw[hh * Ww + w0];
          uint4 mv = *(const uint4*)rr;
          unsigned int lf = (w0 > 0)      ? rr[-1] : 0u;
          unsigned int rt = (w0 < Ww - 4) ? rr[4]  : 0u;
          float am1 = blo(lf),  a0 = blo(mv.x), a1 = blo(mv.y);
          float a2  = blo(mv.z), a3 = blo(mv.w), a4 = blo(rt);
          float bm1 = bhi(lf),  b0 = bhi(mv.x), b1 = bhi(mv.y);
          float b2  = bhi(mv.z), b3 = bhi(mv.w), b4 = bhi(rt);
          float k0a = s9a[(dh + 1) * 3 + 0], k1a = s9a[(dh + 1) * 3 + 1], k2a = s9a[(dh + 1) * 3 + 2];
          float k0b = s9b[(dh + 1) * 3 + 0], k1b = s9b[(dh + 1) * 3 + 1], k2b = s9b[(dh + 1) * 3 + 2];
          sa0 = fmaf(k0a, am1, fmaf(k1a, a0, fmaf(k2a, a1, sa0)));
          sa1 = fmaf(k0a, a0,  fmaf(k1a, a1, fmaf(k2a, a2, sa1)));
          sa2 = fmaf(k0a, a1,  fmaf(k1a, a2, fmaf(k2a, a3, sa2)));
          sa3 = fmaf(k0a, a2,  fmaf(k1a, a3, fmaf(k2a, a4, sa3)));
          sb0 = fmaf(k0b, bm1, fmaf(k1b, b0, fmaf(k2b, b1, sb0)));
          sb1 = fmaf(k0b, b0,  fmaf(k1b, b1, fmaf(k2b, b2, sb1)));
          sb2 = fmaf(k0b, b1,  fmaf(k1b, b2, fmaf(k2b, b3, sb2)));
          sb3 = fmaf(k0b, b2,  fmaf(k1b, b3, fmaf(k2b, b4, sb3)));
        }
        uint4 pk;
        pk.x = pack2(sa0, sb0);
        pk.y = pack2(sa1, sb1);
        pk.z = pack2(sa2, sb2);
        pk.w = pack2(sa3, sb3);
        *(uint4*)&rg[q * 4] = pk;
      }
    }
    __syncthreads();

    int t_out = tt - 1;
    if (t_out >= t0 && t_out <= t0 + 3) {
      unsigned int* zp = zbase + (size_t)t_out * HW;
      for (int q = tid; q < HW / 4; q += 256) {
        float aa0 = tba, aa1 = tba, aa2 = tba, aa3 = tba;
        float bb0 = tbb, bb1 = tbb, bb2 = tbb, bb3 = tbb;
#pragma unroll
        for (int dt = -1; dt <= 1; ++dt) {
          int ti = t_out + dt;
          if (ti < 0 || ti > Tt - 1) continue;
          float tka = ta3[dt + 1], tkb = tb3[dt + 1];
          uint4 v = *(const uint4*)&ring[ti % 3][q * 4];
          aa0 = fmaf(tka, blo(v.x), aa0);  bb0 = fmaf(tkb, bhi(v.x), bb0);
          aa1 = fmaf(tka, blo(v.y), aa1);  bb1 = fmaf(tkb, bhi(v.y), bb1);
          aa2 = fmaf(tka, blo(v.z), aa2);  bb2 = fmaf(tkb, bhi(v.z), bb2);
          aa3 = fmaf(tka, blo(v.w), aa3);  bb3 = fmaf(tkb, bhi(v.w), bb3);
        }
        uint4 o;
        o.x = pack2(aa0, bb0);
        o.y = pack2(aa1, bb1);
        o.z = pack2(aa2, bb2);
        o.w = pack2(aa3, bb3);
        *(uint4*)(zp + q * 4) = o;
      }
    }
    __syncthreads();
  }
}

// ---------------------------------------------------------------------------
// K2/K3: 128 pos x 128 out tile, 4 waves (wave = GN group), 4 subtiles/block,
// double-buffered TRANSPOSED LDS tile zt[128 pos][36 c2-pad]:
//  - staging: 4 scalar coalesced global dwords (one pos, c2-quad) -> one
//    ds_write_b128; (pos + c2q) mod 8 uniform -> conflict-free.
//  - fragment read: ONE ds_read_b128 per MFMA fragment (was 4x ds_read_b32);
//    (lr + lg + 4kt) mod 8 uniform -> conflict-free.
// MFMA: A = z (row = pos), B = W (col = o); lane owns o = lane&15,
// reg-quad = 4 consecutive positions (float4 stores in k3).
// ---------------------------------------------------------------------------
#define WFRAG_LOAD()                                                           \
  const int lr = tid & 15, lg = (tid >> 4) & 3, wv = tid >> 6;                 \
  const int obase = wv * 32;                                                   \
  short8v wfrag[2][2];                                                         \
  _Pragma("unroll")                                                            \
  for (int ot = 0; ot < 2; ++ot)                                               \
    _Pragma("unroll")                                                          \
    for (int kt = 0; kt < 2; ++kt) {                                           \
      int o  = obase + ot * 16 + lr;                                           \
      int c0 = kt * 32 + lg * 8;                                               \
      float4 wa = *(const float4*)(pw + o * 64 + c0);                          \
      float4 wb = *(const float4*)(pw + o * 64 + c0 + 4);                      \
      short8v fr;                                                              \
      fr[0] = (short)f2bf(wa.x); fr[1] = (short)f2bf(wa.y);                    \
      fr[2] = (short)f2bf(wa.z); fr[3] = (short)f2bf(wa.w);                    \
      fr[4] = (short)f2bf(wb.x); fr[5] = (short)f2bf(wb.y);                    \
      fr[6] = (short)f2bf(wb.z); fr[7] = (short)f2bf(wb.w);                    \
      wfrag[ot][kt] = fr;                                                      \
    }

// per-thread staging regs: uint S[4][4]
#define LDT(it, S) {                                                           \
  int p0 = (it) * 128;                                                         \
  _Pragma("unroll")                                                            \
  for (int i = 0; i < 4; ++i) {                                                \
    int f = tid + i * 256; int pos = f & 127; int c2q = f >> 7;                \
    const unsigned int* src = zb + (size_t)(c2q * 4) * THW + p0 + pos;         \
    S[i][0] = src[0];                                                          \
    S[i][1] = src[THW];                                                        \
    S[i][2] = src[2 * THW];                                                    \
    S[i][3] = src[3 * THW];                                                    \
  } }

#define STT(S, bf) {                                                           \
  _Pragma("unroll")                                                            \
  for (int i = 0; i < 4; ++i) {                                                \
    int f = tid + i * 256; int pos = f & 127; int c2q = f >> 7;                \
    *(uint4*)&zt[bf][pos * 36 + c2q * 4] =                                     \
        make_uint4(S[i][0], S[i][1], S[i][2], S[i][3]);                        \
  } }

#define MFMA_TILE(bufidx)                                                      \
  f32x4 acc[2][8];                                                             \
  _Pragma("unroll")                                                            \
  for (int ot = 0; ot < 2; ++ot)                                               \
    _Pragma("unroll")                                                          \
    for (int pt = 0; pt < 8; ++pt) {                                           \
      acc[ot][pt][0] = 0.f; acc[ot][pt][1] = 0.f;                              \
      acc[ot][pt][2] = 0.f; acc[ot][pt][3] = 0.f;                              \
    }                                                                          \
  {                                                                            \
    const unsigned int* ztb = &zt[bufidx][lr * 36 + lg * 4];                   \
    _Pragma("unroll")                                                          \
    for (int kt = 0; kt < 2; ++kt) {                                           \
      _Pragma("unroll")                                                        \
      for (int pt = 0; pt < 8; ++pt) {                                         \
        uint4 zr4 = *(const uint4*)(ztb + pt * (16 * 36) + kt * 16);           \
        union { uint4 u; short8v s; } zfu; zfu.u = zr4;                        \
        acc[0][pt] = __builtin_amdgcn_mfma_f32_16x16x32_bf16(                  \
            zfu.s, wfrag[0][kt], acc[0][pt], 0, 0, 0);                         \
        acc[1][pt] = __builtin_amdgcn_mfma_f32_16x16x32_bf16(                  \
            zfu.s, wfrag[1][kt], acc[1][pt], 0, 0, 0);                         \
      }                                                                        \
    }                                                                          \
  }

#define STATS_BODY()                                                           \
  _Pragma("unroll")                                                            \
  for (int ot = 0; ot < 2; ++ot)                                               \
    _Pragma("unroll")                                                          \
    for (int pt = 0; pt < 8; ++pt)                                             \
      _Pragma("unroll")                                                        \
      for (int r = 0; r < 4; ++r) {                                            \
        float d = acc[ot][pt][r] + pbl[ot];                                    \
        s1 += d;                                                               \
        s2 = fmaf(d, d, s2);                                                   \
      }

// K2: GEMM over 4 subtiles -> per-(b,group) sum / sumsq (double atomics).
__global__ __launch_bounds__(256) void k2_stats(
    const unsigned int* __restrict__ zq, const float* __restrict__ pw,
    const float* __restrict__ pb, double* __restrict__ stats)
{
  __shared__ unsigned int zt[2][128 * 36];   // 36.9 KB
  const int tid = threadIdx.x;
  const int b  = blockIdx.x / 98;
  const int pg = blockIdx.x - b * 98;

  WFRAG_LOAD();
  const float pbl[2] = { pb[obase + lr], pb[obase + 16 + lr] };
  const unsigned int* zb = zq + (size_t)(b * 32) * THW + pg * 512;

  unsigned int st[4][4];
  LDT(0, st); STT(st, 0);

  float s1 = 0.0f, s2 = 0.0f;
  for (int it = 0; it < 4; ++it) {
    __syncthreads();
    if (it < 3) LDT(it + 1, st);
    MFMA_TILE(it & 1);
    if (it < 3) STT(st, (it + 1) & 1);
    STATS_BODY();
  }

#pragma unroll
  for (int off = 32; off; off >>= 1) {
    s1 += __shfl_xor(s1, off);
    s2 += __shfl_xor(s2, off);
  }
  if ((tid & 63) == 0) {
    atomicAdd(&stats[(b * 4 + wv) * 2 + 0], (double)s1);
    atomicAdd(&stats[(b * 4 + wv) * 2 + 1], (double)s2);
  }
}

#define STORE_BODY(itn)                                                        \
  _Pragma("unroll")                                                            \
  for (int ot = 0; ot < 2; ++ot) {                                             \
    int o = obase + ot * 16 + lr;                                              \
    float A = Ac[ot], B = Bc[ot];                                              \
    float* orow = ob + (size_t)o * THW + (itn) * 128;                          \
    _Pragma("unroll")                                                          \
    for (int pt = 0; pt < 8; ++pt) {                                           \
      f32x4 a = acc[ot][pt];                                                   \
      float4 v;                                                                \
      v.x = fmaf(a[0], A, B); v.x = v.x > 0.0f ? v.x : 0.0f;                   \
      v.y = fmaf(a[1], A, B); v.y = v.y > 0.0f ? v.y : 0.0f;                   \
      v.z = fmaf(a[2], A, B); v.z = v.z > 0.0f ? v.z : 0.0f;                   \
      v.w = fmaf(a[3], A, B); v.w = v.w > 0.0f ? v.w : 0.0f;                   \
      *(float4*)(orow + pt * 16) = v;                                          \
    }                                                                          \
  }

// K3: GEMM recompute over 4 subtiles -> GroupNorm + affine + ReLU -> out.
__global__ __launch_bounds__(256) void k3_norm(
    const unsigned int* __restrict__ zq, const float* __restrict__ pw,
    const float* __restrict__ pb, const double* __restrict__ stats,
    const float* __restrict__ gnw, const float* __restrict__ gnb,
    float* __restrict__ out)
{
  __shared__ unsigned int zt[2][128 * 36];
  const int tid = threadIdx.x;
  const int b  = blockIdx.x / 98;
  const int pg = blockIdx.x - b * 98;

  WFRAG_LOAD();

  double sm1 = stats[(b * 4 + wv) * 2 + 0];
  double sm2 = stats[(b * 4 + wv) * 2 + 1];
  double md = sm1 / NPG;
  double vd = sm2 / NPG - md * md;
  float m   = (float)md;
  float inv = rsqrtf((float)vd + 1e-5f);

  float Ac[2], Bc[2];
#pragma unroll
  for (int ot = 0; ot < 2; ++ot) {
    int o = obase + ot * 16 + lr;
    float A = inv * gnw[o];
    Ac[ot] = A;
    Bc[ot] = fmaf(pb[o] - m, A, gnb[o]);
  }

  const unsigned int* zb = zq + (size_t)(b * 32) * THW + pg * 512;
  float* ob = out + (size_t)(b * COUT) * THW + pg * 512 + lg * 4;

  unsigned int st[4][4];
  LDT(0, st); STT(st, 0);

  for (int it = 0; it < 4; ++it) {
    __syncthreads();
    if (it < 3) LDT(it + 1, st);
    MFMA_TILE(it & 1);
    if (it < 3) STT(st, (it + 1) & 1);
    STORE_BODY(it);
  }
}

// ---------------------------------------------------------------------------
extern "C" void kernel_launch(void* const* d_in, const int* in_sizes, int n_in,
                              void* d_out, int out_size, void* d_ws, size_t ws_size,
                              hipStream_t stream)
{
  const float* x   = (const float*)d_in[0];
  const float* sw  = (const float*)d_in[1];
  const float* sb  = (const float*)d_in[2];
  const float* tw  = (const float*)d_in[3];
  const float* tb  = (const float*)d_in[4];
  const float* pw  = (const float*)d_in[5];
  const float* pb  = (const float*)d_in[6];
  const float* gnw = (const float*)d_in[7];
  const float* gnb = (const float*)d_in[8];
  float* out = (float*)d_out;

  double* stats    = (double*)d_ws;                        // 64 doubles
  unsigned int* zq = (unsigned int*)((char*)d_ws + 512);   // bf16-pair z

  k1_dwconv<<<Bb * 32 * 4, 256, 0, stream>>>(x, sw, sb, tw, tb, zq, stats);
  k2_stats<<<Bb * 98, 256, 0, stream>>>(zq, pw, pb, stats);
  k3_norm <<<Bb * 98, 256, 0, stream>>>(zq, pw, pb, stats, gnw, gnb, out);
}

// Round 13
// 147.505 us; speedup vs baseline: 1.3606x; 1.0591x over previous
//
#include <hip/hip_runtime.h>
#include <hip/hip_bf16.h>

#define Bb 8
#define Cc 64
#define Tt 16
#define Hh 56
#define Ww 56
#define COUT 128
#define HW (Hh*Ww)            // 3136
#define THW (Tt*HW)           // 50176
#define NPG ((double)(32*THW))

typedef __attribute__((ext_vector_type(8))) short short8v;   // 8 bf16
typedef __attribute__((ext_vector_type(4))) float f32x4;

__device__ __forceinline__ unsigned short f2bf(float x) {
  __hip_bfloat16 h = __float2bfloat16(x);
  return *reinterpret_cast<unsigned short*>(&h);
}
__device__ __forceinline__ float blo(unsigned int u) {
  return __uint_as_float(u << 16);
}
__device__ __forceinline__ float bhi(unsigned int u) {
  return __uint_as_float(u & 0xFFFF0000u);
}
__device__ __forceinline__ unsigned int pack2(float a, float b) {
  return (unsigned int)f2bf(a) | ((unsigned int)f2bf(b) << 16);
}

// ---------------------------------------------------------------------------
// K1: fused depthwise spatial 3x3 + temporal 3-tap. One block per
// (b, channel-PAIR, t-quad). Raw plane staged in LDS (bf16 pairs); temporal
// accumulation held in REGISTERS (two rolling z-planes per thread) — no ring.
// Per iter: accP += tw2*s -> emit z(tt-1); accP <- accC + tw1*s;
//           accC <- tb + tw0*s.   2 barriers/plane.
// Block 0 zeroes the stats buffer (k2 runs after, stream-ordered).
// ---------------------------------------------------------------------------
__global__ __launch_bounds__(256) void k1_dwconv(
    const float* __restrict__ x,  const float* __restrict__ sw,
    const float* __restrict__ sb, const float* __restrict__ tw,
    const float* __restrict__ tb, unsigned int* __restrict__ zq,
    double* __restrict__ stats)
{
  __shared__ unsigned int raw[HW];        // 12.25 KB (bf16 pair)

  const int tid = threadIdx.x;
  if (blockIdx.x == 0 && tid < 64) stats[tid] = 0.0;

  const int tq = blockIdx.x & 3;
  const int c2 = (blockIdx.x >> 2) & 31;
  const int b  =  blockIdx.x >> 7;
  const int t0 = tq * 4;
  const int ca = c2 * 2, cb = ca + 1;

  float s9a[9], s9b[9];
#pragma unroll
  for (int k = 0; k < 9; ++k) { s9a[k] = sw[ca * 9 + k]; s9b[k] = sw[cb * 9 + k]; }
  const float tw0a = tw[ca * 3 + 0], tw1a = tw[ca * 3 + 1], tw2a = tw[ca * 3 + 2];
  const float tw0b = tw[cb * 3 + 0], tw1b = tw[cb * 3 + 1], tw2b = tw[cb * 3 + 2];
  const float sba = sb[ca], sbb = sb[cb];
  const float tba = tb[ca], tbb = tb[cb];

  const float* xa = x + (size_t)(b * Cc + ca) * THW;
  const float* xb = x + (size_t)(b * Cc + cb) * THW;
  unsigned int* zbase = zq + (size_t)(b * 32 + c2) * THW;

  // rolling accumulators: [chunk][8] = 4 pos ch-a, 4 pos ch-b
  float accP[4][8], accC[4][8];
#pragma unroll
  for (int i = 0; i < 4; ++i)
#pragma unroll
    for (int j = 0; j < 8; ++j) { accP[i][j] = 0.f; accC[i][j] = 0.f; }

  for (int k = 0; k < 6; ++k) {
    const int tt = t0 - 1 + k;
    const bool val = (tt >= 0 && tt < Tt);

    if (val) {
      const float* xpa = xa + tt * HW;
      const float* xpb = xb + tt * HW;
#pragma unroll
      for (int i = 0; i < 4; ++i) {
        int f = tid + i * 256;
        if (f < HW / 4) {
          float4 va = *(const float4*)(xpa + f * 4);
          float4 vb = *(const float4*)(xpb + f * 4);
          uint4 pk;
          pk.x = pack2(va.x, vb.x);
          pk.y = pack2(va.y, vb.y);
          pk.z = pack2(va.z, vb.z);
          pk.w = pack2(va.w, vb.w);
          *(uint4*)&raw[f * 4] = pk;
        }
      }
    }
    __syncthreads();

    const bool emit = (k >= 2);              // t_out = tt-1 in [t0, t0+3]
    const int t_out = tt - 1;
    unsigned int* zp = zbase + (size_t)t_out * HW;

#pragma unroll
    for (int i = 0; i < 4; ++i) {
      int q = tid + i * 256;
      if (q < HW / 4) {
        float s[8];
        if (val) {
          int h  = q / 14;
          int w0 = (q - h * 14) * 4;
          float sa0 = sba, sa1 = sba, sa2 = sba, sa3 = sba;
          float sb0 = sbb, sb1 = sbb, sb2 = sbb, sb3 = sbb;
#pragma unroll
          for (int dh = -1; dh <= 1; ++dh) {
            int hh = h + dh;
            if (hh < 0 || hh > Hh - 1) continue;
            const unsigned int* rr = &raw[hh * Ww + w0];
            uint4 mv = *(const uint4*)rr;
            unsigned int lf = (w0 > 0)      ? rr[-1] : 0u;
            unsigned int rt = (w0 < Ww - 4) ? rr[4]  : 0u;
            float am1 = blo(lf),  a0 = blo(mv.x), a1 = blo(mv.y);
            float a2  = blo(mv.z), a3 = blo(mv.w), a4 = blo(rt);
            float bm1 = bhi(lf),  b0 = bhi(mv.x), b1 = bhi(mv.y);
            float b2  = bhi(mv.z), b3 = bhi(mv.w), b4 = bhi(rt);
            float k0a = s9a[(dh + 1) * 3 + 0], k1a = s9a[(dh + 1) * 3 + 1], k2a = s9a[(dh + 1) * 3 + 2];
            float k0b = s9b[(dh + 1) * 3 + 0], k1b = s9b[(dh + 1) * 3 + 1], k2b = s9b[(dh + 1) * 3 + 2];
            sa0 = fmaf(k0a, am1, fmaf(k1a, a0, fmaf(k2a, a1, sa0)));
            sa1 = fmaf(k0a, a0,  fmaf(k1a, a1, fmaf(k2a, a2, sa1)));
            sa2 = fmaf(k0a, a1,  fmaf(k1a, a2, fmaf(k2a, a3, sa2)));
            sa3 = fmaf(k0a, a2,  fmaf(k1a, a3, fmaf(k2a, a4, sa3)));
            sb0 = fmaf(k0b, bm1, fmaf(k1b, b0, fmaf(k2b, b1, sb0)));
            sb1 = fmaf(k0b, b0,  fmaf(k1b, b1, fmaf(k2b, b2, sb1)));
            sb2 = fmaf(k0b, b1,  fmaf(k1b, b2, fmaf(k2b, b3, sb2)));
            sb3 = fmaf(k0b, b2,  fmaf(k1b, b3, fmaf(k2b, b4, sb3)));
          }
          s[0] = sa0; s[1] = sa1; s[2] = sa2; s[3] = sa3;
          s[4] = sb0; s[5] = sb1; s[6] = sb2; s[7] = sb3;
        } else {
#pragma unroll
          for (int j = 0; j < 8; ++j) s[j] = 0.0f;
        }

        // finalize z(tt-1) and emit
        if (emit) {
          float z0 = fmaf(tw2a, s[0], accP[i][0]);
          float z1 = fmaf(tw2a, s[1], accP[i][1]);
          float z2 = fmaf(tw2a, s[2], accP[i][2]);
          float z3 = fmaf(tw2a, s[3], accP[i][3]);
          float z4 = fmaf(tw2b, s[4], accP[i][4]);
          float z5 = fmaf(tw2b, s[5], accP[i][5]);
          float z6 = fmaf(tw2b, s[6], accP[i][6]);
          float z7 = fmaf(tw2b, s[7], accP[i][7]);
          uint4 o;
          o.x = pack2(z0, z4);
          o.y = pack2(z1, z5);
          o.z = pack2(z2, z6);
          o.w = pack2(z3, z7);
          *(uint4*)(zp + q * 4) = o;
        }
        // roll: accP <- accC + tw1*s ; accC <- tb + tw0*s
#pragma unroll
        for (int j = 0; j < 4; ++j) {
          accP[i][j]     = fmaf(tw1a, s[j],     accC[i][j]);
          accP[i][j + 4] = fmaf(tw1b, s[j + 4], accC[i][j + 4]);
          accC[i][j]     = fmaf(tw0a, s[j],     tba);
          accC[i][j + 4] = fmaf(tw0b, s[j + 4], tbb);
        }
      }
    }
    __syncthreads();   // raw reuse protection (spatial reads done)
  }
}

// ---------------------------------------------------------------------------
// K2/K3: 128 pos x 128 out tile, 4 waves (wave = GN group), 4 subtiles/block,
// double-buffered TRANSPOSED LDS tile zt[128 pos][36 c2-pad]:
//  - staging: 4 scalar coalesced global dwords -> one ds_write_b128.
//  - fragment read: ONE ds_read_b128 per MFMA fragment.
// MFMA: A = z (row = pos), B = W (col = o); lane owns o = lane&15,
// reg-quad = 4 consecutive positions (float4 stores in k3).
// ---------------------------------------------------------------------------
#define WFRAG_LOAD()                                                           \
  const int lr = tid & 15, lg = (tid >> 4) & 3, wv = tid >> 6;                 \
  const int obase = wv * 32;                                                   \
  short8v wfrag[2][2];                                                         \
  _Pragma("unroll")                                                            \
  for (int ot = 0; ot < 2; ++ot)                                               \
    _Pragma("unroll")                                                          \
    for (int kt = 0; kt < 2; ++kt) {                                           \
      int o  = obase + ot * 16 + lr;                                           \
      int c0 = kt * 32 + lg * 8;                                               \
      float4 wa = *(const float4*)(pw + o * 64 + c0);                          \
      float4 wb = *(const float4*)(pw + o * 64 + c0 + 4);                      \
      short8v fr;                                                              \
      fr[0] = (short)f2bf(wa.x); fr[1] = (short)f2bf(wa.y);                    \
      fr[2] = (short)f2bf(wa.z); fr[3] = (short)f2bf(wa.w);                    \
      fr[4] = (short)f2bf(wb.x); fr[5] = (short)f2bf(wb.y);                    \
      fr[6] = (short)f2bf(wb.z); fr[7] = (short)f2bf(wb.w);                    \
      wfrag[ot][kt] = fr;                                                      \
    }

// per-thread staging regs: uint S[4][4]
#define LDT(it, S) {                                                           \
  int p0 = (it) * 128;                                                         \
  _Pragma("unroll")                                                            \
  for (int i = 0; i < 4; ++i) {                                                \
    int f = tid + i * 256; int pos = f & 127; int c2q = f >> 7;                \
    const unsigned int* src = zb + (size_t)(c2q * 4) * THW + p0 + pos;         \
    S[i][0] = src[0];                                                          \
    S[i][1] = src[THW];                                                        \
    S[i][2] = src[2 * THW];                                                    \
    S[i][3] = src[3 * THW];                                                    \
  } }

#define STT(S, bf) {                                                           \
  _Pragma("unroll")                                                            \
  for (int i = 0; i < 4; ++i) {                                                \
    int f = tid + i * 256; int pos = f & 127; int c2q = f >> 7;                \
    *(uint4*)&zt[bf][pos * 36 + c2q * 4] =                                     \
        make_uint4(S[i][0], S[i][1], S[i][2], S[i][3]);                        \
  } }

#define MFMA_TILE(bufidx)                                                      \
  f32x4 acc[2][8];                                                             \
  _Pragma("unroll")                                                            \
  for (int ot = 0; ot < 2; ++ot)                                               \
    _Pragma("unroll")                                                          \
    for (int pt = 0; pt < 8; ++pt) {                                           \
      acc[ot][pt][0] = 0.f; acc[ot][pt][1] = 0.f;                              \
      acc[ot][pt][2] = 0.f; acc[ot][pt][3] = 0.f;                              \
    }                                                                          \
  {                                                                            \
    const unsigned int* ztb = &zt[bufidx][lr * 36 + lg * 4];                   \
    _Pragma("unroll")                                                          \
    for (int kt = 0; kt < 2; ++kt) {                                           \
      _Pragma("unroll")                                                        \
      for (int pt = 0; pt < 8; ++pt) {                                         \
        uint4 zr4 = *(const uint4*)(ztb + pt * (16 * 36) + kt * 16);           \
        union { uint4 u; short8v s; } zfu; zfu.u = zr4;                        \
        acc[0][pt] = __builtin_amdgcn_mfma_f32_16x16x32_bf16(                  \
            zfu.s, wfrag[0][kt], acc[0][pt], 0, 0, 0);                         \
        acc[1][pt] = __builtin_amdgcn_mfma_f32_16x16x32_bf16(                  \
            zfu.s, wfrag[1][kt], acc[1][pt], 0, 0, 0);                         \
      }                                                                        \
    }                                                                          \
  }

#define STATS_BODY()                                                           \
  _Pragma("unroll")                                                            \
  for (int ot = 0; ot < 2; ++ot)                                               \
    _Pragma("unroll")                                                          \
    for (int pt = 0; pt < 8; ++pt)                                             \
      _Pragma("unroll")                                                        \
      for (int r = 0; r < 4; ++r) {                                            \
        float d = acc[ot][pt][r] + pbl[ot];                                    \
        s1 += d;                                                               \
        s2 = fmaf(d, d, s2);                                                   \
      }

// K2: GEMM over 4 subtiles -> per-(b,group) sum / sumsq (double atomics).
__global__ __launch_bounds__(256) void k2_stats(
    const unsigned int* __restrict__ zq, const float* __restrict__ pw,
    const float* __restrict__ pb, double* __restrict__ stats)
{
  __shared__ unsigned int zt[2][128 * 36];   // 36.9 KB
  const int tid = threadIdx.x;
  const int b  = blockIdx.x / 98;
  const int pg = blockIdx.x - b * 98;

  WFRAG_LOAD();
  const float pbl[2] = { pb[obase + lr], pb[obase + 16 + lr] };
  const unsigned int* zb = zq + (size_t)(b * 32) * THW + pg * 512;

  unsigned int st[4][4];
  LDT(0, st); STT(st, 0);

  float s1 = 0.0f, s2 = 0.0f;
  for (int it = 0; it < 4; ++it) {
    __syncthreads();
    if (it < 3) LDT(it + 1, st);
    MFMA_TILE(it & 1);
    if (it < 3) STT(st, (it + 1) & 1);
    STATS_BODY();
  }

#pragma unroll
  for (int off = 32; off; off >>= 1) {
    s1 += __shfl_xor(s1, off);
    s2 += __shfl_xor(s2, off);
  }
  if ((tid & 63) == 0) {
    atomicAdd(&stats[(b * 4 + wv) * 2 + 0], (double)s1);
    atomicAdd(&stats[(b * 4 + wv) * 2 + 1], (double)s2);
  }
}

#define STORE_BODY(itn)                                                        \
  _Pragma("unroll")                                                            \
  for (int ot = 0; ot < 2; ++ot) {                                             \
    int o = obase + ot * 16 + lr;                                              \
    float A = Ac[ot], B = Bc[ot];                                              \
    float* orow = ob + (size_t)o * THW + (itn) * 128;                          \
    _Pragma("unroll")                                                          \
    for (int pt = 0; pt < 8; ++pt) {                                           \
      f32x4 a = acc[ot][pt];                                                   \
      float4 v;                                                                \
      v.x = fmaf(a[0], A, B); v.x = v.x > 0.0f ? v.x : 0.0f;                   \
      v.y = fmaf(a[1], A, B); v.y = v.y > 0.0f ? v.y : 0.0f;                   \
      v.z = fmaf(a[2], A, B); v.z = v.z > 0.0f ? v.z : 0.0f;                   \
      v.w = fmaf(a[3], A, B); v.w = v.w > 0.0f ? v.w : 0.0f;                   \
      *(float4*)(orow + pt * 16) = v;                                          \
    }                                                                          \
  }

// K3: GEMM recompute over 4 subtiles -> GroupNorm + affine + ReLU -> out.
__global__ __launch_bounds__(256) void k3_norm(
    const unsigned int* __restrict__ zq, const float* __restrict__ pw,
    const float* __restrict__ pb, const double* __restrict__ stats,
    const float* __restrict__ gnw, const float* __restrict__ gnb,
    float* __restrict__ out)
{
  __shared__ unsigned int zt[2][128 * 36];
  const int tid = threadIdx.x;
  const int b  = blockIdx.x / 98;
  const int pg = blockIdx.x - b * 98;

  WFRAG_LOAD();

  double sm1 = stats[(b * 4 + wv) * 2 + 0];
  double sm2 = stats[(b * 4 + wv) * 2 + 1];
  double md = sm1 / NPG;
  double vd = sm2 / NPG - md * md;
  float m   = (float)md;
  float inv = rsqrtf((float)vd + 1e-5f);

  float Ac[2], Bc[2];
#pragma unroll
  for (int ot = 0; ot < 2; ++ot) {
    int o = obase + ot * 16 + lr;
    float A = inv * gnw[o];
    Ac[ot] = A;
    Bc[ot] = fmaf(pb[o] - m, A, gnb[o]);
  }

  const unsigned int* zb = zq + (size_t)(b * 32) * THW + pg * 512;
  float* ob = out + (size_t)(b * COUT) * THW + pg * 512 + lg * 4;

  unsigned int st[4][4];
  LDT(0, st); STT(st, 0);

  for (int it = 0; it < 4; ++it) {
    __syncthreads();
    if (it < 3) LDT(it + 1, st);
    MFMA_TILE(it & 1);
    if (it < 3) STT(st, (it + 1) & 1);
    STORE_BODY(it);
  }
}

// ---------------------------------------------------------------------------
extern "C" void kernel_launch(void* const* d_in, const int* in_sizes, int n_in,
                              void* d_out, int out_size, void* d_ws, size_t ws_size,
                              hipStream_t stream)
{
  const float* x   = (const float*)d_in[0];
  const float* sw  = (const float*)d_in[1];
  const float* sb  = (const float*)d_in[2];
  const float* tw  = (const float*)d_in[3];
  const float* tb  = (const float*)d_in[4];
  const float* pw  = (const float*)d_in[5];
  const float* pb  = (const float*)d_in[6];
  const float* gnw = (const float*)d_in[7];
  const float* gnb = (const float*)d_in[8];
  float* out = (float*)d_out;

  double* stats    = (double*)d_ws;                        // 64 doubles
  unsigned int* zq = (unsigned int*)((char*)d_ws + 512);   // bf16-pair z

  k1_dwconv<<<Bb * 32 * 4, 256, 0, stream>>>(x, sw, sb, tw, tb, zq, stats);
  k2_stats<<<Bb * 98, 256, 0, stream>>>(zq, pw, pb, stats);
  k3_norm <<<Bb * 98, 256, 0, stream>>>(zq, pw, pb, stats, gnw, gnb, out);
}

// Round 14
// 145.594 us; speedup vs baseline: 1.3785x; 1.0131x over previous
//
#include <hip/hip_runtime.h>
#include <hip/hip_bf16.h>

#define Bb 8
#define Cc 64
#define Tt 16
#define Hh 56
#define Ww 56
#define COUT 128
#define HW (Hh*Ww)            // 3136
#define THW (Tt*HW)           // 50176
#define NPG ((double)(32*THW))

typedef __attribute__((ext_vector_type(8))) short short8v;   // 8 bf16
typedef __attribute__((ext_vector_type(4))) float f32x4;

__device__ __forceinline__ unsigned short f2bf(float x) {
  __hip_bfloat16 h = __float2bfloat16(x);
  return *reinterpret_cast<unsigned short*>(&h);
}
__device__ __forceinline__ float blo(unsigned int u) {
  return __uint_as_float(u << 16);
}
__device__ __forceinline__ float bhi(unsigned int u) {
  return __uint_as_float(u & 0xFFFF0000u);
}
__device__ __forceinline__ unsigned int pack2(float a, float b) {
  return (unsigned int)f2bf(a) | ((unsigned int)f2bf(b) << 16);
}

// ---------------------------------------------------------------------------
// K1: fused depthwise spatial 3x3 + temporal 3-tap. One block per
// (b, channel-PAIR, t-quad). Raw plane staged in LDS (bf16 pairs); temporal
// accumulation held in REGISTERS (two rolling z-planes per thread) — no ring.
// Block 0 zeroes the stats buffer (k2 runs after, stream-ordered).
// ---------------------------------------------------------------------------
__global__ __launch_bounds__(256) void k1_dwconv(
    const float* __restrict__ x,  const float* __restrict__ sw,
    const float* __restrict__ sb, const float* __restrict__ tw,
    const float* __restrict__ tb, unsigned int* __restrict__ zq,
    double* __restrict__ stats)
{
  __shared__ unsigned int raw[HW];        // 12.25 KB (bf16 pair)

  const int tid = threadIdx.x;
  if (blockIdx.x == 0 && tid < 64) stats[tid] = 0.0;

  const int tq = blockIdx.x & 3;
  const int c2 = (blockIdx.x >> 2) & 31;
  const int b  =  blockIdx.x >> 7;
  const int t0 = tq * 4;
  const int ca = c2 * 2, cb = ca + 1;

  float s9a[9], s9b[9];
#pragma unroll
  for (int k = 0; k < 9; ++k) { s9a[k] = sw[ca * 9 + k]; s9b[k] = sw[cb * 9 + k]; }
  const float tw0a = tw[ca * 3 + 0], tw1a = tw[ca * 3 + 1], tw2a = tw[ca * 3 + 2];
  const float tw0b = tw[cb * 3 + 0], tw1b = tw[cb * 3 + 1], tw2b = tw[cb * 3 + 2];
  const float sba = sb[ca], sbb = sb[cb];
  const float tba = tb[ca], tbb = tb[cb];

  const float* xa = x + (size_t)(b * Cc + ca) * THW;
  const float* xb = x + (size_t)(b * Cc + cb) * THW;
  unsigned int* zbase = zq + (size_t)(b * 32 + c2) * THW;

  float accP[4][8], accC[4][8];
#pragma unroll
  for (int i = 0; i < 4; ++i)
#pragma unroll
    for (int j = 0; j < 8; ++j) { accP[i][j] = 0.f; accC[i][j] = 0.f; }

  for (int k = 0; k < 6; ++k) {
    const int tt = t0 - 1 + k;
    const bool val = (tt >= 0 && tt < Tt);

    if (val) {
      const float* xpa = xa + tt * HW;
      const float* xpb = xb + tt * HW;
#pragma unroll
      for (int i = 0; i < 4; ++i) {
        int f = tid + i * 256;
        if (f < HW / 4) {
          float4 va = *(const float4*)(xpa + f * 4);
          float4 vb = *(const float4*)(xpb + f * 4);
          uint4 pk;
          pk.x = pack2(va.x, vb.x);
          pk.y = pack2(va.y, vb.y);
          pk.z = pack2(va.z, vb.z);
          pk.w = pack2(va.w, vb.w);
          *(uint4*)&raw[f * 4] = pk;
        }
      }
    }
    __syncthreads();

    const bool emit = (k >= 2);
    const int t_out = tt - 1;
    unsigned int* zp = zbase + (size_t)t_out * HW;

#pragma unroll
    for (int i = 0; i < 4; ++i) {
      int q = tid + i * 256;
      if (q < HW / 4) {
        float s[8];
        if (val) {
          int h  = q / 14;
          int w0 = (q - h * 14) * 4;
          float sa0 = sba, sa1 = sba, sa2 = sba, sa3 = sba;
          float sb0 = sbb, sb1 = sbb, sb2 = sbb, sb3 = sbb;
#pragma unroll
          for (int dh = -1; dh <= 1; ++dh) {
            int hh = h + dh;
            if (hh < 0 || hh > Hh - 1) continue;
            const unsigned int* rr = &raw[hh * Ww + w0];
            uint4 mv = *(const uint4*)rr;
            unsigned int lf = (w0 > 0)      ? rr[-1] : 0u;
            unsigned int rt = (w0 < Ww - 4) ? rr[4]  : 0u;
            float am1 = blo(lf),  a0 = blo(mv.x), a1 = blo(mv.y);
            float a2  = blo(mv.z), a3 = blo(mv.w), a4 = blo(rt);
            float bm1 = bhi(lf),  b0 = bhi(mv.x), b1 = bhi(mv.y);
            float b2  = bhi(mv.z), b3 = bhi(mv.w), b4 = bhi(rt);
            float k0a = s9a[(dh + 1) * 3 + 0], k1a = s9a[(dh + 1) * 3 + 1], k2a = s9a[(dh + 1) * 3 + 2];
            float k0b = s9b[(dh + 1) * 3 + 0], k1b = s9b[(dh + 1) * 3 + 1], k2b = s9b[(dh + 1) * 3 + 2];
            sa0 = fmaf(k0a, am1, fmaf(k1a, a0, fmaf(k2a, a1, sa0)));
            sa1 = fmaf(k0a, a0,  fmaf(k1a, a1, fmaf(k2a, a2, sa1)));
            sa2 = fmaf(k0a, a1,  fmaf(k1a, a2, fmaf(k2a, a3, sa2)));
            sa3 = fmaf(k0a, a2,  fmaf(k1a, a3, fmaf(k2a, a4, sa3)));
            sb0 = fmaf(k0b, bm1, fmaf(k1b, b0, fmaf(k2b, b1, sb0)));
            sb1 = fmaf(k0b, b0,  fmaf(k1b, b1, fmaf(k2b, b2, sb1)));
            sb2 = fmaf(k0b, b1,  fmaf(k1b, b2, fmaf(k2b, b3, sb2)));
            sb3 = fmaf(k0b, b2,  fmaf(k1b, b3, fmaf(k2b, b4, sb3)));
          }
          s[0] = sa0; s[1] = sa1; s[2] = sa2; s[3] = sa3;
          s[4] = sb0; s[5] = sb1; s[6] = sb2; s[7] = sb3;
        } else {
#pragma unroll
          for (int j = 0; j < 8; ++j) s[j] = 0.0f;
        }

        if (emit) {
          float z0 = fmaf(tw2a, s[0], accP[i][0]);
          float z1 = fmaf(tw2a, s[1], accP[i][1]);
          float z2 = fmaf(tw2a, s[2], accP[i][2]);
          float z3 = fmaf(tw2a, s[3], accP[i][3]);
          float z4 = fmaf(tw2b, s[4], accP[i][4]);
          float z5 = fmaf(tw2b, s[5], accP[i][5]);
          float z6 = fmaf(tw2b, s[6], accP[i][6]);
          float z7 = fmaf(tw2b, s[7], accP[i][7]);
          uint4 o;
          o.x = pack2(z0, z4);
          o.y = pack2(z1, z5);
          o.z = pack2(z2, z6);
          o.w = pack2(z3, z7);
          *(uint4*)(zp + q * 4) = o;
        }
#pragma unroll
        for (int j = 0; j < 4; ++j) {
          accP[i][j]     = fmaf(tw1a, s[j],     accC[i][j]);
          accP[i][j + 4] = fmaf(tw1b, s[j + 4], accC[i][j + 4]);
          accC[i][j]     = fmaf(tw0a, s[j],     tba);
          accC[i][j + 4] = fmaf(tw0b, s[j + 4], tbb);
        }
      }
    }
    __syncthreads();
  }
}

// ---------------------------------------------------------------------------
// K2/K3: 128 pos x 128 out tile, 4 waves (wave = GN group), 4 subtiles/block,
// double-buffered TRANSPOSED LDS tile zt[128 pos][36 c2-pad].
// MFMA: A = z (row = pos), B = W (col = o); lane owns o = lane&15,
// reg-quad = 4 consecutive positions.
// ---------------------------------------------------------------------------
#define WFRAG_LOAD()                                                           \
  const int lr = tid & 15, lg = (tid >> 4) & 3, wv = tid >> 6;                 \
  const int obase = wv * 32;                                                   \
  short8v wfrag[2][2];                                                         \
  _Pragma("unroll")                                                            \
  for (int ot = 0; ot < 2; ++ot)                                               \
    _Pragma("unroll")                                                          \
    for (int kt = 0; kt < 2; ++kt) {                                           \
      int o  = obase + ot * 16 + lr;                                           \
      int c0 = kt * 32 + lg * 8;                                               \
      float4 wa = *(const float4*)(pw + o * 64 + c0);                          \
      float4 wb = *(const float4*)(pw + o * 64 + c0 + 4);                      \
      short8v fr;                                                              \
      fr[0] = (short)f2bf(wa.x); fr[1] = (short)f2bf(wa.y);                    \
      fr[2] = (short)f2bf(wa.z); fr[3] = (short)f2bf(wa.w);                    \
      fr[4] = (short)f2bf(wb.x); fr[5] = (short)f2bf(wb.y);                    \
      fr[6] = (short)f2bf(wb.z); fr[7] = (short)f2bf(wb.w);                    \
      wfrag[ot][kt] = fr;                                                      \
    }

#define LDT(it, S) {                                                           \
  int p0 = (it) * 128;                                                         \
  _Pragma("unroll")                                                            \
  for (int i = 0; i < 4; ++i) {                                                \
    int f = tid + i * 256; int pos = f & 127; int c2q = f >> 7;                \
    const unsigned int* src = zb + (size_t)(c2q * 4) * THW + p0 + pos;         \
    S[i][0] = src[0];                                                          \
    S[i][1] = src[THW];                                                        \
    S[i][2] = src[2 * THW];                                                    \
    S[i][3] = src[3 * THW];                                                    \
  } }

#define STT(S, bf) {                                                           \
  _Pragma("unroll")                                                            \
  for (int i = 0; i < 4; ++i) {                                                \
    int f = tid + i * 256; int pos = f & 127; int c2q = f >> 7;                \
    *(uint4*)&zt[bf][pos * 36 + c2q * 4] =                                     \
        make_uint4(S[i][0], S[i][1], S[i][2], S[i][3]);                        \
  } }

#define MFMA_TILE(bufidx)                                                      \
  f32x4 acc[2][8];                                                             \
  _Pragma("unroll")                                                            \
  for (int ot = 0; ot < 2; ++ot)                                               \
    _Pragma("unroll")                                                          \
    for (int pt = 0; pt < 8; ++pt) {                                           \
      acc[ot][pt][0] = 0.f; acc[ot][pt][1] = 0.f;                              \
      acc[ot][pt][2] = 0.f; acc[ot][pt][3] = 0.f;                              \
    }                                                                          \
  {                                                                            \
    const unsigned int* ztb = &zt[bufidx][lr * 36 + lg * 4];                   \
    _Pragma("unroll")                                                          \
    for (int kt = 0; kt < 2; ++kt) {                                           \
      _Pragma("unroll")                                                        \
      for (int pt = 0; pt < 8; ++pt) {                                         \
        uint4 zr4 = *(const uint4*)(ztb + pt * (16 * 36) + kt * 16);           \
        union { uint4 u; short8v s; } zfu; zfu.u = zr4;                        \
        acc[0][pt] = __builtin_amdgcn_mfma_f32_16x16x32_bf16(                  \
            zfu.s, wfrag[0][kt], acc[0][pt], 0, 0, 0);                         \
        acc[1][pt] = __builtin_amdgcn_mfma_f32_16x16x32_bf16(                  \
            zfu.s, wfrag[1][kt], acc[1][pt], 0, 0, 0);                         \
      }                                                                        \
    }                                                                          \
  }

// bias-hoisted stats: raw sums only; pb folded in at the end.
#define STATS_BODY()                                                           \
  _Pragma("unroll")                                                            \
  for (int ot = 0; ot < 2; ++ot)                                               \
    _Pragma("unroll")                                                          \
    for (int pt = 0; pt < 8; ++pt)                                             \
      _Pragma("unroll")                                                        \
      for (int r = 0; r < 4; ++r) {                                            \
        float a = acc[ot][pt][r];                                              \
        s1p[ot] += a;                                                          \
        s2p[ot] = fmaf(a, a, s2p[ot]);                                         \
      }

// K2: GEMM over 4 subtiles -> per-(b,group) sum / sumsq (double atomics).
__global__ __launch_bounds__(256) void k2_stats(
    const unsigned int* __restrict__ zq, const float* __restrict__ pw,
    const float* __restrict__ pb, double* __restrict__ stats)
{
  __shared__ unsigned int zt[2][128 * 36];   // 36.9 KB
  const int tid = threadIdx.x;
  const int b  = blockIdx.x / 98;
  const int pg = blockIdx.x - b * 98;

  WFRAG_LOAD();
  const unsigned int* zb = zq + (size_t)(b * 32) * THW + pg * 512;

  unsigned int st[4][4];
  LDT(0, st); STT(st, 0);

  float s1p[2] = {0.f, 0.f}, s2p[2] = {0.f, 0.f};
  for (int it = 0; it < 4; ++it) {
    __syncthreads();
    if (it < 3) LDT(it + 1, st);
    MFMA_TILE(it & 1);
    if (it < 3) STT(st, (it + 1) & 1);
    STATS_BODY();
  }

  // fold bias: n = 128 elements per ot per thread.
  const float pb0 = pb[obase + lr], pb1 = pb[obase + 16 + lr];
  float s1 = (fmaf(128.f, pb0, s1p[0])) + (fmaf(128.f, pb1, s1p[1]));
  float s2 = (s2p[0] + fmaf(2.f * pb0, s1p[0], 128.f * pb0 * pb0))
           + (s2p[1] + fmaf(2.f * pb1, s1p[1], 128.f * pb1 * pb1));

#pragma unroll
  for (int off = 32; off; off >>= 1) {
    s1 += __shfl_xor(s1, off);
    s2 += __shfl_xor(s2, off);
  }
  if ((tid & 63) == 0) {
    atomicAdd(&stats[(b * 4 + wv) * 2 + 0], (double)s1);
    atomicAdd(&stats[(b * 4 + wv) * 2 + 1], (double)s2);
  }
}

#define STORE_BODY(itn)                                                        \
  _Pragma("unroll")                                                            \
  for (int ot = 0; ot < 2; ++ot) {                                             \
    int o = obase + ot * 16 + lr;                                              \
    float A = Ac[ot], B = Bc[ot];                                              \
    float* orow = ob + (size_t)o * THW + (itn) * 128;                          \
    _Pragma("unroll")                                                          \
    for (int pt = 0; pt < 8; ++pt) {                                           \
      f32x4 a = acc[ot][pt];                                                   \
      float4 v;                                                                \
      v.x = fmaf(a[0], A, B); v.x = v.x > 0.0f ? v.x : 0.0f;                   \
      v.y = fmaf(a[1], A, B); v.y = v.y > 0.0f ? v.y : 0.0f;                   \
      v.z = fmaf(a[2], A, B); v.z = v.z > 0.0f ? v.z : 0.0f;                   \
      v.w = fmaf(a[3], A, B); v.w = v.w > 0.0f ? v.w : 0.0f;                   \
      *(float4*)(orow + pt * 16) = v;                                          \
    }                                                                          \
  }

// K3: GEMM recompute over 4 subtiles -> GroupNorm + affine + ReLU -> out.
__global__ __launch_bounds__(256) void k3_norm(
    const unsigned int* __restrict__ zq, const float* __restrict__ pw,
    const float* __restrict__ pb, const double* __restrict__ stats,
    const float* __restrict__ gnw, const float* __restrict__ gnb,
    float* __restrict__ out)
{
  __shared__ unsigned int zt[2][128 * 36];
  const int tid = threadIdx.x;
  const int b  = blockIdx.x / 98;
  const int pg = blockIdx.x - b * 98;

  WFRAG_LOAD();

  double sm1 = stats[(b * 4 + wv) * 2 + 0];
  double sm2 = stats[(b * 4 + wv) * 2 + 1];
  double md = sm1 / NPG;
  double vd = sm2 / NPG - md * md;
  float m   = (float)md;
  float inv = rsqrtf((float)vd + 1e-5f);

  float Ac[2], Bc[2];
#pragma unroll
  for (int ot = 0; ot < 2; ++ot) {
    int o = obase + ot * 16 + lr;
    float A = inv * gnw[o];
    Ac[ot] = A;
    Bc[ot] = fmaf(pb[o] - m, A, gnb[o]);
  }

  const unsigned int* zb = zq + (size_t)(b * 32) * THW + pg * 512;
  float* ob = out + (size_t)(b * COUT) * THW + pg * 512 + lg * 4;

  unsigned int st[4][4];
  LDT(0, st); STT(st, 0);

  for (int it = 0; it < 4; ++it) {
    __syncthreads();
    if (it < 3) LDT(it + 1, st);
    MFMA_TILE(it & 1);
    if (it < 3) STT(st, (it + 1) & 1);
    STORE_BODY(it);
  }
}

// ---------------------------------------------------------------------------
extern "C" void kernel_launch(void* const* d_in, const int* in_sizes, int n_in,
                              void* d_out, int out_size, void* d_ws, size_t ws_size,
                              hipStream_t stream)
{
  const float* x   = (const float*)d_in[0];
  const float* sw  = (const float*)d_in[1];
  const float* sb  = (const float*)d_in[2];
  const float* tw  = (const float*)d_in[3];
  const float* tb  = (const float*)d_in[4];
  const float* pw  = (const float*)d_in[5];
  const float* pb  = (const float*)d_in[6];
  const float* gnw = (const float*)d_in[7];
  const float* gnb = (const float*)d_in[8];
  float* out = (float*)d_out;

  double* stats    = (double*)d_ws;                        // 64 doubles
  unsigned int* zq = (unsigned int*)((char*)d_ws + 512);   // bf16-pair z

  k1_dwconv<<<Bb * 32 * 4, 256, 0, stream>>>(x, sw, sb, tw, tb, zq, stats);
  k2_stats<<<Bb * 98, 256, 0, stream>>>(zq, pw, pb, stats);
  k3_norm <<<Bb * 98, 256, 0, stream>>>(zq, pw, pb, stats, gnw, gnb, out);
}

// Round 15
// 138.148 us; speedup vs baseline: 1.4528x; 1.0539x over previous
//
#include <hip/hip_runtime.h>
#include <hip/hip_bf16.h>

#define Bb 8
#define Cc 64
#define Tt 16
#define Hh 56
#define Ww 56
#define COUT 128
#define HW (Hh*Ww)            // 3136
#define THW (Tt*HW)           // 50176
#define NPG ((double)(32*THW))

typedef __attribute__((ext_vector_type(8))) short short8v;   // 8 bf16
typedef __attribute__((ext_vector_type(4))) float f32x4;

__device__ __forceinline__ unsigned short f2bf(float x) {
  __hip_bfloat16 h = __float2bfloat16(x);
  return *reinterpret_cast<unsigned short*>(&h);
}
__device__ __forceinline__ float blo(unsigned int u) {
  return __uint_as_float(u << 16);
}
__device__ __forceinline__ float bhi(unsigned int u) {
  return __uint_as_float(u & 0xFFFF0000u);
}
__device__ __forceinline__ unsigned int pack2(float a, float b) {
  return (unsigned int)f2bf(a) | ((unsigned int)f2bf(b) << 16);
}

// ---------------------------------------------------------------------------
// K1: fused depthwise spatial 3x3 + temporal 3-tap. One block per
// (b, channel-PAIR, t-HALF (8 planes)). Raw plane staged in LDS (bf16 pairs);
// temporal accumulation in registers (two rolling z-planes) — no ring.
// 10 planes spatially convolved per block, 8 emitted (1.25x redundancy,
// was 1.5x at t-quad=4). Block 0 zeroes the stats buffer.
// ---------------------------------------------------------------------------
__global__ __launch_bounds__(256) void k1_dwconv(
    const float* __restrict__ x,  const float* __restrict__ sw,
    const float* __restrict__ sb, const float* __restrict__ tw,
    const float* __restrict__ tb, unsigned int* __restrict__ zq,
    double* __restrict__ stats)
{
  __shared__ unsigned int raw[HW];        // 12.25 KB (bf16 pair)

  const int tid = threadIdx.x;
  if (blockIdx.x == 0 && tid < 64) stats[tid] = 0.0;

  const int tq = blockIdx.x & 1;
  const int c2 = (blockIdx.x >> 1) & 31;
  const int b  =  blockIdx.x >> 6;
  const int t0 = tq * 8;
  const int ca = c2 * 2, cb = ca + 1;

  float s9a[9], s9b[9];
#pragma unroll
  for (int k = 0; k < 9; ++k) { s9a[k] = sw[ca * 9 + k]; s9b[k] = sw[cb * 9 + k]; }
  const float tw0a = tw[ca * 3 + 0], tw1a = tw[ca * 3 + 1], tw2a = tw[ca * 3 + 2];
  const float tw0b = tw[cb * 3 + 0], tw1b = tw[cb * 3 + 1], tw2b = tw[cb * 3 + 2];
  const float sba = sb[ca], sbb = sb[cb];
  const float tba = tb[ca], tbb = tb[cb];

  const float* xa = x + (size_t)(b * Cc + ca) * THW;
  const float* xb = x + (size_t)(b * Cc + cb) * THW;
  unsigned int* zbase = zq + (size_t)(b * 32 + c2) * THW;

  float accP[4][8], accC[4][8];
#pragma unroll
  for (int i = 0; i < 4; ++i)
#pragma unroll
    for (int j = 0; j < 8; ++j) { accP[i][j] = 0.f; accC[i][j] = 0.f; }

  for (int k = 0; k < 10; ++k) {
    const int tt = t0 - 1 + k;
    const bool val = (tt >= 0 && tt < Tt);

    if (val) {
      const float* xpa = xa + tt * HW;
      const float* xpb = xb + tt * HW;
#pragma unroll
      for (int i = 0; i < 4; ++i) {
        int f = tid + i * 256;
        if (f < HW / 4) {
          float4 va = *(const float4*)(xpa + f * 4);
          float4 vb = *(const float4*)(xpb + f * 4);
          uint4 pk;
          pk.x = pack2(va.x, vb.x);
          pk.y = pack2(va.y, vb.y);
          pk.z = pack2(va.z, vb.z);
          pk.w = pack2(va.w, vb.w);
          *(uint4*)&raw[f * 4] = pk;
        }
      }
    }
    __syncthreads();

    const bool emit = (k >= 2);
    const int t_out = tt - 1;
    unsigned int* zp = zbase + (size_t)t_out * HW;

#pragma unroll
    for (int i = 0; i < 4; ++i) {
      int q = tid + i * 256;
      if (q < HW / 4) {
        float s[8];
        if (val) {
          int h  = q / 14;
          int w0 = (q - h * 14) * 4;
          float sa0 = sba, sa1 = sba, sa2 = sba, sa3 = sba;
          float sb0 = sbb, sb1 = sbb, sb2 = sbb, sb3 = sbb;
#pragma unroll
          for (int dh = -1; dh <= 1; ++dh) {
            int hh = h + dh;
            if (hh < 0 || hh > Hh - 1) continue;
            const unsigned int* rr = &raw[hh * Ww + w0];
            uint4 mv = *(const uint4*)rr;
            unsigned int lf = (w0 > 0)      ? rr[-1] : 0u;
            unsigned int rt = (w0 < Ww - 4) ? rr[4]  : 0u;
            float am1 = blo(lf),  a0 = blo(mv.x), a1 = blo(mv.y);
            float a2  = blo(mv.z), a3 = blo(mv.w), a4 = blo(rt);
            float bm1 = bhi(lf),  b0 = bhi(mv.x), b1 = bhi(mv.y);
            float b2  = bhi(mv.z), b3 = bhi(mv.w), b4 = bhi(rt);
            float k0a = s9a[(dh + 1) * 3 + 0], k1a = s9a[(dh + 1) * 3 + 1], k2a = s9a[(dh + 1) * 3 + 2];
            float k0b = s9b[(dh + 1) * 3 + 0], k1b = s9b[(dh + 1) * 3 + 1], k2b = s9b[(dh + 1) * 3 + 2];
            sa0 = fmaf(k0a, am1, fmaf(k1a, a0, fmaf(k2a, a1, sa0)));
            sa1 = fmaf(k0a, a0,  fmaf(k1a, a1, fmaf(k2a, a2, sa1)));
            sa2 = fmaf(k0a, a1,  fmaf(k1a, a2, fmaf(k2a, a3, sa2)));
            sa3 = fmaf(k0a, a2,  fmaf(k1a, a3, fmaf(k2a, a4, sa3)));
            sb0 = fmaf(k0b, bm1, fmaf(k1b, b0, fmaf(k2b, b1, sb0)));
            sb1 = fmaf(k0b, b0,  fmaf(k1b, b1, fmaf(k2b, b2, sb1)));
            sb2 = fmaf(k0b, b1,  fmaf(k1b, b2, fmaf(k2b, b3, sb2)));
            sb3 = fmaf(k0b, b2,  fmaf(k1b, b3, fmaf(k2b, b4, sb3)));
          }
          s[0] = sa0; s[1] = sa1; s[2] = sa2; s[3] = sa3;
          s[4] = sb0; s[5] = sb1; s[6] = sb2; s[7] = sb3;
        } else {
#pragma unroll
          for (int j = 0; j < 8; ++j) s[j] = 0.0f;
        }

        if (emit) {
          float z0 = fmaf(tw2a, s[0], accP[i][0]);
          float z1 = fmaf(tw2a, s[1], accP[i][1]);
          float z2 = fmaf(tw2a, s[2], accP[i][2]);
          float z3 = fmaf(tw2a, s[3], accP[i][3]);
          float z4 = fmaf(tw2b, s[4], accP[i][4]);
          float z5 = fmaf(tw2b, s[5], accP[i][5]);
          float z6 = fmaf(tw2b, s[6], accP[i][6]);
          float z7 = fmaf(tw2b, s[7], accP[i][7]);
          uint4 o;
          o.x = pack2(z0, z4);
          o.y = pack2(z1, z5);
          o.z = pack2(z2, z6);
          o.w = pack2(z3, z7);
          *(uint4*)(zp + q * 4) = o;
        }
#pragma unroll
        for (int j = 0; j < 4; ++j) {
          accP[i][j]     = fmaf(tw1a, s[j],     accC[i][j]);
          accP[i][j + 4] = fmaf(tw1b, s[j + 4], accC[i][j + 4]);
          accC[i][j]     = fmaf(tw0a, s[j],     tba);
          accC[i][j + 4] = fmaf(tw0b, s[j + 4], tbb);
        }
      }
    }
    __syncthreads();
  }
}

// ---------------------------------------------------------------------------
// K2/K3: 128 pos x 128 out tile, 4 waves (wave = GN group), 4 subtiles/block,
// double-buffered TRANSPOSED LDS tile zt[128 pos][36 c2-pad].
// MFMA: A = z (row = pos), B = W (col = o); lane owns o = lane&15,
// reg-quad = 4 consecutive positions.
// ---------------------------------------------------------------------------
#define WFRAG_LOAD()                                                           \
  const int lr = tid & 15, lg = (tid >> 4) & 3, wv = tid >> 6;                 \
  const int obase = wv * 32;                                                   \
  short8v wfrag[2][2];                                                         \
  _Pragma("unroll")                                                            \
  for (int ot = 0; ot < 2; ++ot)                                               \
    _Pragma("unroll")                                                          \
    for (int kt = 0; kt < 2; ++kt) {                                           \
      int o  = obase + ot * 16 + lr;                                           \
      int c0 = kt * 32 + lg * 8;                                               \
      float4 wa = *(const float4*)(pw + o * 64 + c0);                          \
      float4 wb = *(const float4*)(pw + o * 64 + c0 + 4);                      \
      short8v fr;                                                              \
      fr[0] = (short)f2bf(wa.x); fr[1] = (short)f2bf(wa.y);                    \
      fr[2] = (short)f2bf(wa.z); fr[3] = (short)f2bf(wa.w);                    \
      fr[4] = (short)f2bf(wb.x); fr[5] = (short)f2bf(wb.y);                    \
      fr[6] = (short)f2bf(wb.z); fr[7] = (short)f2bf(wb.w);                    \
      wfrag[ot][kt] = fr;                                                      \
    }

#define LDT(it, S) {                                                           \
  int p0 = (it) * 128;                                                         \
  _Pragma("unroll")                                                            \
  for (int i = 0; i < 4; ++i) {                                                \
    int f = tid + i * 256; int pos = f & 127; int c2q = f >> 7;                \
    const unsigned int* src = zb + (size_t)(c2q * 4) * THW + p0 + pos;         \
    S[i][0] = src[0];                                                          \
    S[i][1] = src[THW];                                                        \
    S[i][2] = src[2 * THW];                                                    \
    S[i][3] = src[3 * THW];                                                    \
  } }

#define STT(S, bf) {                                                           \
  _Pragma("unroll")                                                            \
  for (int i = 0; i < 4; ++i) {                                                \
    int f = tid + i * 256; int pos = f & 127; int c2q = f >> 7;                \
    *(uint4*)&zt[bf][pos * 36 + c2q * 4] =                                     \
        make_uint4(S[i][0], S[i][1], S[i][2], S[i][3]);                        \
  } }

#define MFMA_TILE(bufidx)                                                      \
  f32x4 acc[2][8];                                                             \
  _Pragma("unroll")                                                            \
  for (int ot = 0; ot < 2; ++ot)                                               \
    _Pragma("unroll")                                                          \
    for (int pt = 0; pt < 8; ++pt) {                                           \
      acc[ot][pt][0] = 0.f; acc[ot][pt][1] = 0.f;                              \
      acc[ot][pt][2] = 0.f; acc[ot][pt][3] = 0.f;                              \
    }                                                                          \
  {                                                                            \
    const unsigned int* ztb = &zt[bufidx][lr * 36 + lg * 4];                   \
    _Pragma("unroll")                                                          \
    for (int kt = 0; kt < 2; ++kt) {                                           \
      _Pragma("unroll")                                                        \
      for (int pt = 0; pt < 8; ++pt) {                                         \
        uint4 zr4 = *(const uint4*)(ztb + pt * (16 * 36) + kt * 16);           \
        union { uint4 u; short8v s; } zfu; zfu.u = zr4;                        \
        acc[0][pt] = __builtin_amdgcn_mfma_f32_16x16x32_bf16(                  \
            zfu.s, wfrag[0][kt], acc[0][pt], 0, 0, 0);                         \
        acc[1][pt] = __builtin_amdgcn_mfma_f32_16x16x32_bf16(                  \
            zfu.s, wfrag[1][kt], acc[1][pt], 0, 0, 0);                         \
      }                                                                        \
    }                                                                          \
  }

// bias-hoisted stats: raw sums only; pb folded in at the end.
#define STATS_BODY()                                                           \
  _Pragma("unroll")                                                            \
  for (int ot = 0; ot < 2; ++ot)                                               \
    _Pragma("unroll")                                                          \
    for (int pt = 0; pt < 8; ++pt)                                             \
      _Pragma("unroll")                                                        \
      for (int r = 0; r < 4; ++r) {                                            \
        float a = acc[ot][pt][r];                                              \
        s1p[ot] += a;                                                          \
        s2p[ot] = fmaf(a, a, s2p[ot]);                                         \
      }

// K2: GEMM over 4 subtiles -> per-(b,group) sum / sumsq (double atomics).
__global__ __launch_bounds__(256) void k2_stats(
    const unsigned int* __restrict__ zq, const float* __restrict__ pw,
    const float* __restrict__ pb, double* __restrict__ stats)
{
  __shared__ unsigned int zt[2][128 * 36];   // 36.9 KB
  const int tid = threadIdx.x;
  const int b  = blockIdx.x / 98;
  const int pg = blockIdx.x - b * 98;

  WFRAG_LOAD();
  const unsigned int* zb = zq + (size_t)(b * 32) * THW + pg * 512;

  unsigned int st[4][4];
  LDT(0, st); STT(st, 0);

  float s1p[2] = {0.f, 0.f}, s2p[2] = {0.f, 0.f};
  for (int it = 0; it < 4; ++it) {
    __syncthreads();
    if (it < 3) LDT(it + 1, st);
    MFMA_TILE(it & 1);
    if (it < 3) STT(st, (it + 1) & 1);
    STATS_BODY();
  }

  const float pb0 = pb[obase + lr], pb1 = pb[obase + 16 + lr];
  float s1 = (fmaf(128.f, pb0, s1p[0])) + (fmaf(128.f, pb1, s1p[1]));
  float s2 = (s2p[0] + fmaf(2.f * pb0, s1p[0], 128.f * pb0 * pb0))
           + (s2p[1] + fmaf(2.f * pb1, s1p[1], 128.f * pb1 * pb1));

#pragma unroll
  for (int off = 32; off; off >>= 1) {
    s1 += __shfl_xor(s1, off);
    s2 += __shfl_xor(s2, off);
  }
  if ((tid & 63) == 0) {
    atomicAdd(&stats[(b * 4 + wv) * 2 + 0], (double)s1);
    atomicAdd(&stats[(b * 4 + wv) * 2 + 1], (double)s2);
  }
}

#define STORE_BODY(itn)                                                        \
  _Pragma("unroll")                                                            \
  for (int ot = 0; ot < 2; ++ot) {                                             \
    int o = obase + ot * 16 + lr;                                              \
    float A = Ac[ot], B = Bc[ot];                                              \
    float* orow = ob + (size_t)o * THW + (itn) * 128;                          \
    _Pragma("unroll")                                                          \
    for (int pt = 0; pt < 8; ++pt) {                                           \
      f32x4 a = acc[ot][pt];                                                   \
      float4 v;                                                                \
      v.x = fmaf(a[0], A, B); v.x = v.x > 0.0f ? v.x : 0.0f;                   \
      v.y = fmaf(a[1], A, B); v.y = v.y > 0.0f ? v.y : 0.0f;                   \
      v.z = fmaf(a[2], A, B); v.z = v.z > 0.0f ? v.z : 0.0f;                   \
      v.w = fmaf(a[3], A, B); v.w = v.w > 0.0f ? v.w : 0.0f;                   \
      *(float4*)(orow + pt * 16) = v;                                          \
    }                                                                          \
  }

// K3: GEMM recompute over 4 subtiles -> GroupNorm + affine + ReLU -> out.
__global__ __launch_bounds__(256) void k3_norm(
    const unsigned int* __restrict__ zq, const float* __restrict__ pw,
    const float* __restrict__ pb, const double* __restrict__ stats,
    const float* __restrict__ gnw, const float* __restrict__ gnb,
    float* __restrict__ out)
{
  __shared__ unsigned int zt[2][128 * 36];
  const int tid = threadIdx.x;
  const int b  = blockIdx.x / 98;
  const int pg = blockIdx.x - b * 98;

  WFRAG_LOAD();

  double sm1 = stats[(b * 4 + wv) * 2 + 0];
  double sm2 = stats[(b * 4 + wv) * 2 + 1];
  double md = sm1 / NPG;
  double vd = sm2 / NPG - md * md;
  float m   = (float)md;
  float inv = rsqrtf((float)vd + 1e-5f);

  float Ac[2], Bc[2];
#pragma unroll
  for (int ot = 0; ot < 2; ++ot) {
    int o = obase + ot * 16 + lr;
    float A = inv * gnw[o];
    Ac[ot] = A;
    Bc[ot] = fmaf(pb[o] - m, A, gnb[o]);
  }

  const unsigned int* zb = zq + (size_t)(b * 32) * THW + pg * 512;
  float* ob = out + (size_t)(b * COUT) * THW + pg * 512 + lg * 4;

  unsigned int st[4][4];
  LDT(0, st); STT(st, 0);

  for (int it = 0; it < 4; ++it) {
    __syncthreads();
    if (it < 3) LDT(it + 1, st);
    MFMA_TILE(it & 1);
    if (it < 3) STT(st, (it + 1) & 1);
    STORE_BODY(it);
  }
}

// ---------------------------------------------------------------------------
extern "C" void kernel_launch(void* const* d_in, const int* in_sizes, int n_in,
                              void* d_out, int out_size, void* d_ws, size_t ws_size,
                              hipStream_t stream)
{
  const float* x   = (const float*)d_in[0];
  const float* sw  = (const float*)d_in[1];
  const float* sb  = (const float*)d_in[2];
  const float* tw  = (const float*)d_in[3];
  const float* tb  = (const float*)d_in[4];
  const float* pw  = (const float*)d_in[5];
  const float* pb  = (const float*)d_in[6];
  const float* gnw = (const float*)d_in[7];
  const float* gnb = (const float*)d_in[8];
  float* out = (float*)d_out;

  double* stats    = (double*)d_ws;                        // 64 doubles
  unsigned int* zq = (unsigned int*)((char*)d_ws + 512);   // bf16-pair z

  k1_dwconv<<<Bb * 32 * 2, 256, 0, stream>>>(x, sw, sb, tw, tb, zq, stats); // 512
  k2_stats<<<Bb * 98, 256, 0, stream>>>(zq, pw, pb, stats);
  k3_norm <<<Bb * 98, 256, 0, stream>>>(zq, pw, pb, stats, gnw, gnb, out);
}

// Round 16
// 137.506 us; speedup vs baseline: 1.4596x; 1.0047x over previous
//
#include <hip/hip_runtime.h>
#include <hip/hip_bf16.h>

#define Bb 8
#define Cc 64
#define Tt 16
#define Hh 56
#define Ww 56
#define COUT 128
#define HW (Hh*Ww)            // 3136
#define THW (Tt*HW)           // 50176
#define NPG ((double)(32*THW))

typedef __attribute__((ext_vector_type(8))) short short8v;   // 8 bf16
typedef __attribute__((ext_vector_type(4))) float f32x4;

__device__ __forceinline__ unsigned short f2bf(float x) {
  __hip_bfloat16 h = __float2bfloat16(x);
  return *reinterpret_cast<unsigned short*>(&h);
}
__device__ __forceinline__ float blo(unsigned int u) {
  return __uint_as_float(u << 16);
}
__device__ __forceinline__ float bhi(unsigned int u) {
  return __uint_as_float(u & 0xFFFF0000u);
}
__device__ __forceinline__ unsigned int pack2(float a, float b) {
  return (unsigned int)f2bf(a) | ((unsigned int)f2bf(b) << 16);
}

// ---------------------------------------------------------------------------
// K1: fused depthwise spatial 3x3 + temporal 3-tap. One block per
// (b, channel-PAIR, t-HALF). Raw plane DOUBLE-BUFFERED in LDS (bf16 pairs)
// -> ONE barrier per plane (write-release; skew bounded by the barrier so
// buffer k&1 is never written while still being read). Temporal accumulation
// in registers (two rolling z-planes). Block 0 zeroes the stats buffer.
// ---------------------------------------------------------------------------
__global__ __launch_bounds__(256) void k1_dwconv(
    const float* __restrict__ x,  const float* __restrict__ sw,
    const float* __restrict__ sb, const float* __restrict__ tw,
    const float* __restrict__ tb, unsigned int* __restrict__ zq,
    double* __restrict__ stats)
{
  __shared__ unsigned int raw[2][HW];     // 24.5 KB (bf16 pair, dbuf)

  const int tid = threadIdx.x;
  if (blockIdx.x == 0 && tid < 64) stats[tid] = 0.0;

  const int tq = blockIdx.x & 1;
  const int c2 = (blockIdx.x >> 1) & 31;
  const int b  =  blockIdx.x >> 6;
  const int t0 = tq * 8;
  const int ca = c2 * 2, cb = ca + 1;

  float s9a[9], s9b[9];
#pragma unroll
  for (int k = 0; k < 9; ++k) { s9a[k] = sw[ca * 9 + k]; s9b[k] = sw[cb * 9 + k]; }
  const float tw0a = tw[ca * 3 + 0], tw1a = tw[ca * 3 + 1], tw2a = tw[ca * 3 + 2];
  const float tw0b = tw[cb * 3 + 0], tw1b = tw[cb * 3 + 1], tw2b = tw[cb * 3 + 2];
  const float sba = sb[ca], sbb = sb[cb];
  const float tba = tb[ca], tbb = tb[cb];

  const float* xa = x + (size_t)(b * Cc + ca) * THW;
  const float* xb = x + (size_t)(b * Cc + cb) * THW;
  unsigned int* zbase = zq + (size_t)(b * 32 + c2) * THW;

  float accP[4][8], accC[4][8];
#pragma unroll
  for (int i = 0; i < 4; ++i)
#pragma unroll
    for (int j = 0; j < 8; ++j) { accP[i][j] = 0.f; accC[i][j] = 0.f; }

  for (int k = 0; k < 10; ++k) {
    const int tt = t0 - 1 + k;
    const bool val = (tt >= 0 && tt < Tt);
    unsigned int* rw = raw[k & 1];

    if (val) {
      const float* xpa = xa + tt * HW;
      const float* xpb = xb + tt * HW;
#pragma unroll
      for (int i = 0; i < 4; ++i) {
        int f = tid + i * 256;
        if (f < HW / 4) {
          float4 va = *(const float4*)(xpa + f * 4);
          float4 vb = *(const float4*)(xpb + f * 4);
          uint4 pk;
          pk.x = pack2(va.x, vb.x);
          pk.y = pack2(va.y, vb.y);
          pk.z = pack2(va.z, vb.z);
          pk.w = pack2(va.w, vb.w);
          *(uint4*)&rw[f * 4] = pk;
        }
      }
    }
    __syncthreads();   // the ONLY barrier per plane

    const bool emit = (k >= 2);
    const int t_out = tt - 1;
    unsigned int* zp = zbase + (size_t)t_out * HW;

#pragma unroll
    for (int i = 0; i < 4; ++i) {
      int q = tid + i * 256;
      if (q < HW / 4) {
        float s[8];
        if (val) {
          int h  = q / 14;
          int w0 = (q - h * 14) * 4;
          float sa0 = sba, sa1 = sba, sa2 = sba, sa3 = sba;
          float sb0 = sbb, sb1 = sbb, sb2 = sbb, sb3 = sbb;
#pragma unroll
          for (int dh = -1; dh <= 1; ++dh) {
            int hh = h + dh;
            if (hh < 0 || hh > Hh - 1) continue;
            const unsigned int* rr = &rw[hh * Ww + w0];
            uint4 mv = *(const uint4*)rr;
            unsigned int lf = (w0 > 0)      ? rr[-1] : 0u;
            unsigned int rt = (w0 < Ww - 4) ? rr[4]  : 0u;
            float am1 = blo(lf),  a0 = blo(mv.x), a1 = blo(mv.y);
            float a2  = blo(mv.z), a3 = blo(mv.w), a4 = blo(rt);
            float bm1 = bhi(lf),  b0 = bhi(mv.x), b1 = bhi(mv.y);
            float b2  = bhi(mv.z), b3 = bhi(mv.w), b4 = bhi(rt);
            float k0a = s9a[(dh + 1) * 3 + 0], k1a = s9a[(dh + 1) * 3 + 1], k2a = s9a[(dh + 1) * 3 + 2];
            float k0b = s9b[(dh + 1) * 3 + 0], k1b = s9b[(dh + 1) * 3 + 1], k2b = s9b[(dh + 1) * 3 + 2];
            sa0 = fmaf(k0a, am1, fmaf(k1a, a0, fmaf(k2a, a1, sa0)));
            sa1 = fmaf(k0a, a0,  fmaf(k1a, a1, fmaf(k2a, a2, sa1)));
            sa2 = fmaf(k0a, a1,  fmaf(k1a, a2, fmaf(k2a, a3, sa2)));
            sa3 = fmaf(k0a, a2,  fmaf(k1a, a3, fmaf(k2a, a4, sa3)));
            sb0 = fmaf(k0b, bm1, fmaf(k1b, b0, fmaf(k2b, b1, sb0)));
            sb1 = fmaf(k0b, b0,  fmaf(k1b, b1, fmaf(k2b, b2, sb1)));
            sb2 = fmaf(k0b, b1,  fmaf(k1b, b2, fmaf(k2b, b3, sb2)));
            sb3 = fmaf(k0b, b2,  fmaf(k1b, b3, fmaf(k2b, b4, sb3)));
          }
          s[0] = sa0; s[1] = sa1; s[2] = sa2; s[3] = sa3;
          s[4] = sb0; s[5] = sb1; s[6] = sb2; s[7] = sb3;
        } else {
#pragma unroll
          for (int j = 0; j < 8; ++j) s[j] = 0.0f;
        }

        if (emit) {
          float z0 = fmaf(tw2a, s[0], accP[i][0]);
          float z1 = fmaf(tw2a, s[1], accP[i][1]);
          float z2 = fmaf(tw2a, s[2], accP[i][2]);
          float z3 = fmaf(tw2a, s[3], accP[i][3]);
          float z4 = fmaf(tw2b, s[4], accP[i][4]);
          float z5 = fmaf(tw2b, s[5], accP[i][5]);
          float z6 = fmaf(tw2b, s[6], accP[i][6]);
          float z7 = fmaf(tw2b, s[7], accP[i][7]);
          uint4 o;
          o.x = pack2(z0, z4);
          o.y = pack2(z1, z5);
          o.z = pack2(z2, z6);
          o.w = pack2(z3, z7);
          *(uint4*)(zp + q * 4) = o;
        }
#pragma unroll
        for (int j = 0; j < 4; ++j) {
          accP[i][j]     = fmaf(tw1a, s[j],     accC[i][j]);
          accP[i][j + 4] = fmaf(tw1b, s[j + 4], accC[i][j + 4]);
          accC[i][j]     = fmaf(tw0a, s[j],     tba);
          accC[i][j + 4] = fmaf(tw0b, s[j + 4], tbb);
        }
      }
    }
    // no trailing barrier: next iteration writes the OTHER raw buffer,
    // and its post-stage barrier bounds wave skew.
  }
}

// ---------------------------------------------------------------------------
// K2/K3: 128 pos x 128 out tile, 4 waves (wave = GN group), 4 subtiles/block,
// double-buffered TRANSPOSED LDS tile zt[128 pos][36 c2-pad].
// MFMA: A = z (row = pos), B = W (col = o); lane owns o = lane&15,
// reg-quad = 4 consecutive positions.
// ---------------------------------------------------------------------------
#define WFRAG_LOAD()                                                           \
  const int lr = tid & 15, lg = (tid >> 4) & 3, wv = tid >> 6;                 \
  const int obase = wv * 32;                                                   \
  short8v wfrag[2][2];                                                         \
  _Pragma("unroll")                                                            \
  for (int ot = 0; ot < 2; ++ot)                                               \
    _Pragma("unroll")                                                          \
    for (int kt = 0; kt < 2; ++kt) {                                           \
      int o  = obase + ot * 16 + lr;                                           \
      int c0 = kt * 32 + lg * 8;                                               \
      float4 wa = *(const float4*)(pw + o * 64 + c0);                          \
      float4 wb = *(const float4*)(pw + o * 64 + c0 + 4);                      \
      short8v fr;                                                              \
      fr[0] = (short)f2bf(wa.x); fr[1] = (short)f2bf(wa.y);                    \
      fr[2] = (short)f2bf(wa.z); fr[3] = (short)f2bf(wa.w);                    \
      fr[4] = (short)f2bf(wb.x); fr[5] = (short)f2bf(wb.y);                    \
      fr[6] = (short)f2bf(wb.z); fr[7] = (short)f2bf(wb.w);                    \
      wfrag[ot][kt] = fr;                                                      \
    }

#define LDT(it, S) {                                                           \
  int p0 = (it) * 128;                                                         \
  _Pragma("unroll")                                                            \
  for (int i = 0; i < 4; ++i) {                                                \
    int f = tid + i * 256; int pos = f & 127; int c2q = f >> 7;                \
    const unsigned int* src = zb + (size_t)(c2q * 4) * THW + p0 + pos;         \
    S[i][0] = src[0];                                                          \
    S[i][1] = src[THW];                                                        \
    S[i][2] = src[2 * THW];                                                    \
    S[i][3] = src[3 * THW];                                                    \
  } }

#define STT(S, bf) {                                                           \
  _Pragma("unroll")                                                            \
  for (int i = 0; i < 4; ++i) {                                                \
    int f = tid + i * 256; int pos = f & 127; int c2q = f >> 7;                \
    *(uint4*)&zt[bf][pos * 36 + c2q * 4] =                                     \
        make_uint4(S[i][0], S[i][1], S[i][2], S[i][3]);                        \
  } }

#define MFMA_TILE(bufidx)                                                      \
  f32x4 acc[2][8];                                                             \
  _Pragma("unroll")                                                            \
  for (int ot = 0; ot < 2; ++ot)                                               \
    _Pragma("unroll")                                                          \
    for (int pt = 0; pt < 8; ++pt) {                                           \
      acc[ot][pt][0] = 0.f; acc[ot][pt][1] = 0.f;                              \
      acc[ot][pt][2] = 0.f; acc[ot][pt][3] = 0.f;                              \
    }                                                                          \
  {                                                                            \
    const unsigned int* ztb = &zt[bufidx][lr * 36 + lg * 4];                   \
    _Pragma("unroll")                                                          \
    for (int kt = 0; kt < 2; ++kt) {                                           \
      _Pragma("unroll")                                                        \
      for (int pt = 0; pt < 8; ++pt) {                                         \
        uint4 zr4 = *(const uint4*)(ztb + pt * (16 * 36) + kt * 16);           \
        union { uint4 u; short8v s; } zfu; zfu.u = zr4;                        \
        acc[0][pt] = __builtin_amdgcn_mfma_f32_16x16x32_bf16(                  \
            zfu.s, wfrag[0][kt], acc[0][pt], 0, 0, 0);                         \
        acc[1][pt] = __builtin_amdgcn_mfma_f32_16x16x32_bf16(                  \
            zfu.s, wfrag[1][kt], acc[1][pt], 0, 0, 0);                         \
      }                                                                        \
    }                                                                          \
  }

// bias-hoisted stats: raw sums only; pb folded in at the end.
#define STATS_BODY()                                                           \
  _Pragma("unroll")                                                            \
  for (int ot = 0; ot < 2; ++ot)                                               \
    _Pragma("unroll")                                                          \
    for (int pt = 0; pt < 8; ++pt)                                             \
      _Pragma("unroll")                                                        \
      for (int r = 0; r < 4; ++r) {                                            \
        float a = acc[ot][pt][r];                                              \
        s1p[ot] += a;                                                          \
        s2p[ot] = fmaf(a, a, s2p[ot]);                                         \
      }

// K2: GEMM over 4 subtiles -> per-(b,group) sum / sumsq (double atomics).
__global__ __launch_bounds__(256) void k2_stats(
    const unsigned int* __restrict__ zq, const float* __restrict__ pw,
    const float* __restrict__ pb, double* __restrict__ stats)
{
  __shared__ unsigned int zt[2][128 * 36];   // 36.9 KB
  const int tid = threadIdx.x;
  const int b  = blockIdx.x / 98;
  const int pg = blockIdx.x - b * 98;

  WFRAG_LOAD();
  const unsigned int* zb = zq + (size_t)(b * 32) * THW + pg * 512;

  unsigned int st[4][4];
  LDT(0, st); STT(st, 0);

  float s1p[2] = {0.f, 0.f}, s2p[2] = {0.f, 0.f};
  for (int it = 0; it < 4; ++it) {
    __syncthreads();
    if (it < 3) LDT(it + 1, st);
    MFMA_TILE(it & 1);
    if (it < 3) STT(st, (it + 1) & 1);
    STATS_BODY();
  }

  const float pb0 = pb[obase + lr], pb1 = pb[obase + 16 + lr];
  float s1 = (fmaf(128.f, pb0, s1p[0])) + (fmaf(128.f, pb1, s1p[1]));
  float s2 = (s2p[0] + fmaf(2.f * pb0, s1p[0], 128.f * pb0 * pb0))
           + (s2p[1] + fmaf(2.f * pb1, s1p[1], 128.f * pb1 * pb1));

#pragma unroll
  for (int off = 32; off; off >>= 1) {
    s1 += __shfl_xor(s1, off);
    s2 += __shfl_xor(s2, off);
  }
  if ((tid & 63) == 0) {
    atomicAdd(&stats[(b * 4 + wv) * 2 + 0], (double)s1);
    atomicAdd(&stats[(b * 4 + wv) * 2 + 1], (double)s2);
  }
}

#define STORE_BODY(itn)                                                        \
  _Pragma("unroll")                                                            \
  for (int ot = 0; ot < 2; ++ot) {                                             \
    int o = obase + ot * 16 + lr;                                              \
    float A = Ac[ot], B = Bc[ot];                                              \
    float* orow = ob + (size_t)o * THW + (itn) * 128;                          \
    _Pragma("unroll")                                                          \
    for (int pt = 0; pt < 8; ++pt) {                                           \
      f32x4 a = acc[ot][pt];                                                   \
      float4 v;                                                                \
      v.x = fmaf(a[0], A, B); v.x = v.x > 0.0f ? v.x : 0.0f;                   \
      v.y = fmaf(a[1], A, B); v.y = v.y > 0.0f ? v.y : 0.0f;                   \
      v.z = fmaf(a[2], A, B); v.z = v.z > 0.0f ? v.z : 0.0f;                   \
      v.w = fmaf(a[3], A, B); v.w = v.w > 0.0f ? v.w : 0.0f;                   \
      *(float4*)(orow + pt * 16) = v;                                          \
    }                                                                          \
  }

// K3: GEMM recompute over 4 subtiles -> GroupNorm + affine + ReLU -> out.
__global__ __launch_bounds__(256) void k3_norm(
    const unsigned int* __restrict__ zq, const float* __restrict__ pw,
    const float* __restrict__ pb, const double* __restrict__ stats,
    const float* __restrict__ gnw, const float* __restrict__ gnb,
    float* __restrict__ out)
{
  __shared__ unsigned int zt[2][128 * 36];
  const int tid = threadIdx.x;
  const int b  = blockIdx.x / 98;
  const int pg = blockIdx.x - b * 98;

  WFRAG_LOAD();

  double sm1 = stats[(b * 4 + wv) * 2 + 0];
  double sm2 = stats[(b * 4 + wv) * 2 + 1];
  double md = sm1 / NPG;
  double vd = sm2 / NPG - md * md;
  float m   = (float)md;
  float inv = rsqrtf((float)vd + 1e-5f);

  float Ac[2], Bc[2];
#pragma unroll
  for (int ot = 0; ot < 2; ++ot) {
    int o = obase + ot * 16 + lr;
    float A = inv * gnw[o];
    Ac[ot] = A;
    Bc[ot] = fmaf(pb[o] - m, A, gnb[o]);
  }

  const unsigned int* zb = zq + (size_t)(b * 32) * THW + pg * 512;
  float* ob = out + (size_t)(b * COUT) * THW + pg * 512 + lg * 4;

  unsigned int st[4][4];
  LDT(0, st); STT(st, 0);

  for (int it = 0; it < 4; ++it) {
    __syncthreads();
    if (it < 3) LDT(it + 1, st);
    MFMA_TILE(it & 1);
    if (it < 3) STT(st, (it + 1) & 1);
    STORE_BODY(it);
  }
}

// ---------------------------------------------------------------------------
extern "C" void kernel_launch(void* const* d_in, const int* in_sizes, int n_in,
                              void* d_out, int out_size, void* d_ws, size_t ws_size,
                              hipStream_t stream)
{
  const float* x   = (const float*)d_in[0];
  const float* sw  = (const float*)d_in[1];
  const float* sb  = (const float*)d_in[2];
  const float* tw  = (const float*)d_in[3];
  const float* tb  = (const float*)d_in[4];
  const float* pw  = (const float*)d_in[5];
  const float* pb  = (const float*)d_in[6];
  const float* gnw = (const float*)d_in[7];
  const float* gnb = (const float*)d_in[8];
  float* out = (float*)d_out;

  double* stats    = (double*)d_ws;                        // 64 doubles
  unsigned int* zq = (unsigned int*)((char*)d_ws + 512);   // bf16-pair z

  k1_dwconv<<<Bb * 32 * 2, 256, 0, stream>>>(x, sw, sb, tw, tb, zq, stats); // 512
  k2_stats<<<Bb * 98, 256, 0, stream>>>(zq, pw, pb, stats);
  k3_norm <<<Bb * 98, 256, 0, stream>>>(zq, pw, pb, stats, gnw, gnb, out);
}